// Round 6
// baseline (164.273 us; speedup 1.0000x reference)
//
#include <hip/hip_runtime.h>

// b=16, n=m=2048, d=dv=128, fp32 in/out, temp=sqrt(128).
// Prep: K -> bf16 scaled by log2e/temp; V -> Vt[b][dv][m] bf16. Q cast in-kernel.
// Attention: swapped S^T = K.Q^T via 32x32x16 bf16 MFMA, P = exp2(S),
// P->A-frag via v_cvt_pk_bf16_f32 + v_permlane32_swap_b32, PV accumulate.
// Round-6: K LEAVES LDS. Each wave loads its K fragments (16B/lane, contiguous
// in Kb) straight from L2 into registers, prefetch-distance = the PV phase.
// V stays LDS-staged (shared by the 2 q-waves), TRIPLE-buffered (48KB).
// PV-lag pipeline, ONE raw s_barrier per tile, NO explicit vmcnt:
//   body t: s_barrier ; issue kf(t) loads ; STAGE_V(t+1) ; PV(t-1) ; QK(t) ; SM(t)
// The compiler's counted wait for kf(t) (vmcnt(4): only V(t+1) newer) also
// drains V(t) one body before PV(t) reads it -> cross-wave V visibility is
// [each wave's kf-wait] + [next body's barrier]. Buffer-overwrite safety:
// STAGE_V(t+1) targets vbuf[(t+1)%3], last read by PV(t-2) in body t-1,
// ordered by this body's barrier. Removes: K LDS write+read (-50% LDS
// traffic), one barrier/tile, K-path bank conflicts.
// Block = 4 waves: 2 q-waves (BQ=64) x 2 m-waves (BK=64 split 32/32).
// Grid 16x32 = 512 blocks -> 2 blocks/CU, 8 waves/CU.

#define BATCH 16
#define SEQ   2048
#define DIM   128
#define NT    (SEQ / 64)

typedef short bf16x8 __attribute__((ext_vector_type(8)));
typedef float f32x16 __attribute__((ext_vector_type(16)));

static __device__ __forceinline__ unsigned pk2(float lo, float hi) {
  union { float f; unsigned u; } a, b;
  a.f = lo; b.f = hi;
  return ((b.u + 0x8000u) & 0xffff0000u) | ((a.u + 0x8000u) >> 16);
}
static __device__ __forceinline__ float fast_exp2(float x) {
#if __has_builtin(__builtin_amdgcn_exp2f)
  return __builtin_amdgcn_exp2f(x);
#else
  return exp2f(x);
#endif
}

typedef __attribute__((address_space(1))) const unsigned int g_u32;
typedef __attribute__((address_space(3))) unsigned int l_u32;
static __device__ __forceinline__ void gl2lds16(const unsigned short* g, unsigned short* l) {
  // per-lane global src; wave-uniform LDS base, HW writes base + lane*16
  __builtin_amdgcn_global_load_lds((g_u32*)g, (l_u32*)l, 16, 0, 0);
}

// ---- fused preprocess: blocks [0,2048): K cvt+scale; [2048,3072): V transpose ----
__global__ __launch_bounds__(256)
void prep_kernel(const float* __restrict__ K, const float* __restrict__ V,
                 unsigned short* __restrict__ Kb, unsigned short* __restrict__ Vt,
                 float scale) {
  const int bx = blockIdx.x, tid = threadIdx.x;
  if (bx < 2048) {
    size_t idx = (size_t)bx * 256 + tid;
    const float4* kf = (const float4*)K;
    float4 a = kf[idx * 2], c = kf[idx * 2 + 1];
    uint4 o;
    o.x = pk2(a.x * scale, a.y * scale);
    o.y = pk2(a.z * scale, a.w * scale);
    o.z = pk2(c.x * scale, c.y * scale);
    o.w = pk2(c.z * scale, c.w * scale);
    ((uint4*)Kb)[idx] = o;
  } else {
    __shared__ float tile[128][33];
    const int vb = bx - 2048;                 // 1024 blocks
    const int b = vb >> 6, r = vb & 63;
    const int m0 = (r & 15) * 128, d0 = (r >> 4) * 32;
    const int c = tid & 7, mr = tid >> 3;
    const float* src = V + ((size_t)(b * SEQ) + m0) * DIM + d0;
#pragma unroll
    for (int it = 0; it < 4; ++it) {
      int m = it * 32 + mr;
      float4 x = *(const float4*)(src + (size_t)m * DIM + c * 4);
      tile[m][c * 4 + 0] = x.x; tile[m][c * 4 + 1] = x.y;
      tile[m][c * 4 + 2] = x.z; tile[m][c * 4 + 3] = x.w;
    }
    __syncthreads();
    const int dr = tid >> 3, s = tid & 7;
    unsigned short* dst = Vt + ((size_t)(b * DIM) + d0 + dr) * SEQ + m0;
#pragma unroll
    for (int it = 0; it < 2; ++it) {
      int slot = it * 8 + s;
      uint4 o;
      o.x = pk2(tile[slot * 8 + 0][dr], tile[slot * 8 + 1][dr]);
      o.y = pk2(tile[slot * 8 + 2][dr], tile[slot * 8 + 3][dr]);
      o.z = pk2(tile[slot * 8 + 4][dr], tile[slot * 8 + 5][dr]);
      o.w = pk2(tile[slot * 8 + 6][dr], tile[slot * 8 + 7][dr]);
      *(uint4*)(dst + slot * 8) = o;
    }
  }
}

// ---- main flash attention ----
// LDS (bytes): V bufs @0, @16384, @32768 (3x16KB = 49152 total).
// V buf: 128 rows x 128B linear, [row][x] holds Vt[row][m0 + (x ^ ((row&7)<<4))/2]
// Epilogue (after __syncthreads) aliases: cb f32[2][4096] @0, cbL @32768 (512B).

__global__ __launch_bounds__(256, 2)
void attn_kernel(const float* __restrict__ Qf,
                 const unsigned short* __restrict__ Kb,
                 const unsigned short* __restrict__ Vtb,
                 float* __restrict__ out) {
  __shared__ __align__(1024) unsigned char smem[49152];
  unsigned short* sm16 = (unsigned short*)smem;

  const int tid  = threadIdx.x;
  const int wv   = tid >> 6;
  const int w_q  = wv & 1;                  // q-subtile (32 rows)
  const int w_m  = wv >> 1;                 // m-half (32 cols) of the 64-tile
  const int lane = tid & 63;
  const int l31  = lane & 31;
  const int q2   = lane >> 5;
  const int b    = blockIdx.x;
  const int q0   = blockIdx.y * 64 + w_q * 32;

  const unsigned short* kb = Kb  + (size_t)b * SEQ * DIM;   // [m][d], pre-scaled
  const unsigned short* vb = Vtb + (size_t)b * SEQ * DIM;   // [dv][m]

  // Q fragments (B-operand of swapped QK^T): lane (l31,q2) holds Q[q0+l31][c*16+q2*8+j]
  bf16x8 aq[8];
  {
    const float* qp = Qf + ((size_t)(b * SEQ) + q0 + l31) * DIM + q2 * 8;
#pragma unroll
    for (int c = 0; c < 8; ++c) {
      float4 x = *(const float4*)(qp + c * 16);
      float4 y = *(const float4*)(qp + c * 16 + 4);
      union { unsigned i[4]; bf16x8 v; } u;
      u.i[0] = pk2(x.x, x.y); u.i[1] = pk2(x.z, x.w);
      u.i[2] = pk2(y.x, y.y); u.i[3] = pk2(y.z, y.w);
      aq[c] = u.v;
    }
  }

  // K per-wave register load base: lane (l31,q2) reads K[m0 + w_m*32 + l31][c*16 + q2*8 ..]
  const unsigned short* kwp = kb + ((size_t)((w_m << 5) + l31) << 7) + (q2 << 3);

  // V staging source offsets (ushort units); LDS dest linear, global src pre-swizzled
  unsigned vgo[4];
#pragma unroll
  for (int i = 0; i < 4; ++i) {
    int ch = wv * 4 + i;
    int vrow = ch * 8 + (lane >> 3);
    vgo[i] = (unsigned)(vrow * 2048) + ((((lane & 7) << 4) ^ ((vrow & 7) << 4)) >> 1);
  }
  // swizzled V read base offset (bytes, within a buffer)
  const int vro = (l31 << 7) + (((w_m << 6) + (q2 << 4)) ^ ((l31 & 7) << 4));

  f32x16 oacc[4];
#pragma unroll
  for (int t = 0; t < 4; ++t)
#pragma unroll
    for (int i = 0; i < 16; ++i) oacc[t][i] = 0.0f;
  float ls[4] = {0.0f, 0.0f, 0.0f, 0.0f};

#define STAGE_V(TV, VOFF) do {                                               \
    const unsigned short* vt_b = vb + ((TV) << 6);                           \
    unsigned short* vd = sm16 + (((VOFF) + wv * 4096) >> 1);                 \
    _Pragma("unroll")                                                        \
    for (int i = 0; i < 4; ++i) gl2lds16(vt_b + vgo[i], vd + i * 512);       \
  } while (0)

#define LOADK(TK) do {                                                       \
    const unsigned short* kp = kwp + ((size_t)(TK) << 13);                   \
    _Pragma("unroll")                                                        \
    for (int c = 0; c < 8; ++c) kf[c] = *(const bf16x8*)(kp + c * 16);       \
  } while (0)

#define QK() do {                                                            \
    _Pragma("unroll")                                                        \
    for (int i = 0; i < 16; ++i) { se[i] = 0.0f; so[i] = 0.0f; }             \
    __builtin_amdgcn_s_setprio(1);                                           \
    _Pragma("unroll")                                                        \
    for (int c = 0; c < 4; ++c) {                                            \
      se = __builtin_amdgcn_mfma_f32_32x32x16_bf16(kf[2 * c],     aq[2 * c],     se, 0, 0, 0); \
      so = __builtin_amdgcn_mfma_f32_32x32x16_bf16(kf[2 * c + 1], aq[2 * c + 1], so, 0, 0, 0); \
    }                                                                        \
    __builtin_amdgcn_s_setprio(0);                                           \
  } while (0)

#define SOFTMAX() do {                                                       \
    float p[16];                                                             \
    _Pragma("unroll")                                                        \
    for (int i = 0; i < 16; ++i) p[i] = fast_exp2(se[i] + so[i]);            \
    _Pragma("unroll")                                                        \
    for (int i = 0; i < 4; ++i) {                                            \
      ls[0] += p[4 * i + 0]; ls[1] += p[4 * i + 1];                          \
      ls[2] += p[4 * i + 2]; ls[3] += p[4 * i + 3];                          \
    }                                                                        \
    unsigned d0, d1, d2, d3, d4, d5, d6, d7;                                 \
    asm("v_cvt_pk_bf16_f32 %0, %1, %2" : "=v"(d0) : "v"(p[0]),  "v"(p[1]));  \
    asm("v_cvt_pk_bf16_f32 %0, %1, %2" : "=v"(d1) : "v"(p[2]),  "v"(p[3]));  \
    asm("v_cvt_pk_bf16_f32 %0, %1, %2" : "=v"(d2) : "v"(p[4]),  "v"(p[5]));  \
    asm("v_cvt_pk_bf16_f32 %0, %1, %2" : "=v"(d3) : "v"(p[6]),  "v"(p[7]));  \
    asm("v_cvt_pk_bf16_f32 %0, %1, %2" : "=v"(d4) : "v"(p[8]),  "v"(p[9]));  \
    asm("v_cvt_pk_bf16_f32 %0, %1, %2" : "=v"(d5) : "v"(p[10]), "v"(p[11])); \
    asm("v_cvt_pk_bf16_f32 %0, %1, %2" : "=v"(d6) : "v"(p[12]), "v"(p[13])); \
    asm("v_cvt_pk_bf16_f32 %0, %1, %2" : "=v"(d7) : "v"(p[14]), "v"(p[15])); \
    asm("v_permlane32_swap_b32 %0, %1" : "+v"(d0), "+v"(d2));                \
    asm("v_permlane32_swap_b32 %0, %1" : "+v"(d1), "+v"(d3));                \
    asm("v_permlane32_swap_b32 %0, %1" : "+v"(d4), "+v"(d6));                \
    asm("v_permlane32_swap_b32 %0, %1" : "+v"(d5), "+v"(d7));                \
    pu0.u[0] = d0; pu0.u[1] = d1; pu0.u[2] = d2; pu0.u[3] = d3;              \
    pu1.u[0] = d4; pu1.u[1] = d5; pu1.u[2] = d6; pu1.u[3] = d7;              \
  } while (0)

#define PV(VOFF) do {                                                        \
    const unsigned char* vB_ = smem + (VOFF);                                \
    __builtin_amdgcn_s_setprio(1);                                           \
    _Pragma("unroll")                                                        \
    for (int t = 0; t < 4; ++t) {                                            \
      bf16x8 bv0 = *(const bf16x8*)(vB_ + t * 4096 + vro);                   \
      oacc[t] = __builtin_amdgcn_mfma_f32_32x32x16_bf16(pu0.v, bv0, oacc[t], 0, 0, 0); \
      bf16x8 bv1 = *(const bf16x8*)(vB_ + t * 4096 + (vro ^ 32));            \
      oacc[t] = __builtin_amdgcn_mfma_f32_32x32x16_bf16(pu1.v, bv1, oacc[t], 0, 0, 0); \
    }                                                                        \
    __builtin_amdgcn_s_setprio(0);                                           \
  } while (0)

  bf16x8 kf[8];
  f32x16 se, so;
  union { unsigned u[4]; bf16x8 v; } pu0, pu1;

  // ---- prologue: V(0) staged+drained; QK(0)+softmax(0); V(1) in flight ----
  STAGE_V(0, 0);
  LOADK(0);
  __syncthreads();                          // drains V(0)+kf(0); V(0) visible
  STAGE_V(1, 16384);
  QK();
  SOFTMAX();                                // -> pu(0)

  int pv_off  = 0;                          // vbuf[(t-1)%3]
  int stg_off = 32768;                      // vbuf[(t+1)%3]

#pragma unroll 1
  for (int kt = 1; kt < NT; ++kt) {
    __builtin_amdgcn_s_barrier();           // all waves: PV(kt-2) done
    __builtin_amdgcn_sched_barrier(0);

    LOADK(kt);                              // kf(kt): lands under PV
    if (kt < NT - 1) STAGE_V(kt + 1, stg_off);

    PV(pv_off);                             // PV(kt-1) with pu(kt-1)
    QK();                                   // compiler waits kf (vmcnt counted)
    SOFTMAX();                              // -> pu(kt)

    pv_off  = (pv_off  == 32768) ? 0 : pv_off  + 16384;
    stg_off = (stg_off == 32768) ? 0 : stg_off + 16384;
  }

  // ---- epilogue PV(NT-1): all waves passed kf(NT-1) wait => V(NT-1) landed ----
  __builtin_amdgcn_s_barrier();
  __builtin_amdgcn_sched_barrier(0);
  PV(16384);                                // vbuf[(NT-1)%3] = 1

#undef STAGE_V
#undef LOADK
#undef QK
#undef SOFTMAX
#undef PV

  float lsum = (ls[0] + ls[1]) + (ls[2] + ls[3]);
  // merge q2 halves of the row sum: lane (l31,*) -> sum over this wave's 32 m
  lsum += __shfl_xor(lsum, 32, 64);

  // combine the two m-halves through LDS, normalize, coalesced store
  __syncthreads();                          // all tile reads done before aliasing
  float* cb  = (float*)smem;                // [2][64][64] partials = 32768 B
  float* cbL = (float*)(smem + 32768);      // [2][64] row sums
  if (w_m == 1) {
    float* my = cb + w_q * 4096;
#pragma unroll
    for (int t = 0; t < 4; ++t)
#pragma unroll
      for (int r = 0; r < 16; ++r)
        my[(t * 16 + r) * 64 + lane] = oacc[t][r];
  }
  cbL[w_m * 64 + w_q * 32 + l31] = lsum;    // both q2 lanes write same value
  __syncthreads();
  if (w_m == 0) {
    const float* pr = cb + w_q * 4096;
    float linv[16];
#pragma unroll
    for (int r = 0; r < 16; ++r) {
      int qr = (r & 3) + ((r >> 2) << 3) + (q2 << 2);
      linv[r] = 1.0f / (cbL[w_q * 32 + qr] + cbL[64 + w_q * 32 + qr]);
    }
    float* ob = out + ((size_t)(b * SEQ) + q0) * DIM;
#pragma unroll
    for (int t = 0; t < 4; ++t)
#pragma unroll
      for (int r = 0; r < 16; ++r) {
        int qr = (r & 3) + ((r >> 2) << 3) + (q2 << 2);
        ob[(size_t)qr * DIM + t * 32 + l31] = (oacc[t][r] + pr[(t * 16 + r) * 64 + lane]) * linv[r];
      }
  }
}

extern "C" void kernel_launch(void* const* d_in, const int* in_sizes, int n_in,
                              void* d_out, int out_size, void* d_ws, size_t ws_size,
                              hipStream_t stream) {
  const float* Q = (const float*)d_in[0];
  const float* K = (const float*)d_in[1];
  const float* V = (const float*)d_in[2];
  float* out = (float*)d_out;

  const size_t elems = (size_t)BATCH * SEQ * DIM;   // 4,194,304
  unsigned short* Kb = (unsigned short*)d_ws;       // 8 MB
  unsigned short* Vt = Kb + elems;                  // 8 MB (ws >= 16 MB)

  const double TEMPERATURE = 11.313708498984761;
  const float scale = (float)(1.4426950408889634 / TEMPERATURE);  // log2(e)/temp on K

  prep_kernel<<<3072, 256, 0, stream>>>(K, V, Kb, Vt, scale);
  attn_kernel<<<dim3(BATCH, SEQ / 64), 256, 0, stream>>>(Q, Kb, Vt, out);
}

// Round 7
// 149.146 us; speedup vs baseline: 1.1014x; 1.1014x over previous
//
#include <hip/hip_runtime.h>

// b=16, n=m=2048, d=dv=128, fp32 in/out, temp=sqrt(128).
// Prep: K -> bf16 scaled by log2e/temp; V -> Vt[b][dv][m] bf16. Q cast in-kernel.
// Round-7: BARRIER-FREE main loop via wave-private LDS slices.
//   Re-tile: BQ=32/block, BK=128 (NT=16), 4 waves = 4-way m-split (w_m=wv).
//   Per tile, wave w reads ONLY K rows [w*32..+31] (8KB) and V m-cols
//   [w-quarter] (8KB) -> each wave DMA-stages its own private 16KB slice and
//   orders it with private vmcnt/lgkmcnt. NO s_barrier in the main loop:
//   8 waves/CU free-run and de-phase (R4/R5 showed the wall is lockstepped
//   phase serialization, not load latency). Partial O (over m-quarter) and
//   partial row-sums are merged 4-way in a short LDS epilogue (1 barrier).
//   MFMA / LDS / HBM totals identical to the R4 kernel; only sync changes.
//   Per-wave body: vmcnt(0) [my K,V landed] -> K->regs -> lgkmcnt(0) ->
//   STAGE_K(t+1) -> QK -> softmax -> PV (direct ds_read) -> lgkmcnt(0) ->
//   STAGE_V(t+1).  (R6 lesson: scattered per-lane global loads are 64-address
//   TA poison; all staging stays on the linear global_load_lds DMA path.)
// Grid 1024 blocks (16 batch x 64 q-chunks), XCD-swizzled so each XCD's L2
// holds 2 batches' K/V (~2MB). 66.5KB LDS -> 2 blocks/CU, 8 waves/CU.

#define BATCH 16
#define SEQ   2048
#define DIM   128
#define NT    (SEQ / 128)

typedef short bf16x8 __attribute__((ext_vector_type(8)));
typedef float f32x16 __attribute__((ext_vector_type(16)));

static __device__ __forceinline__ unsigned pk2(float lo, float hi) {
  union { float f; unsigned u; } a, b;
  a.f = lo; b.f = hi;
  return ((b.u + 0x8000u) & 0xffff0000u) | ((a.u + 0x8000u) >> 16);
}
static __device__ __forceinline__ float fast_exp2(float x) {
#if __has_builtin(__builtin_amdgcn_exp2f)
  return __builtin_amdgcn_exp2f(x);
#else
  return exp2f(x);
#endif
}

typedef __attribute__((address_space(1))) const unsigned int g_u32;
typedef __attribute__((address_space(3))) unsigned int l_u32;
static __device__ __forceinline__ void gl2lds16(const unsigned short* g, unsigned short* l) {
  // per-lane global src; wave-uniform LDS base, HW writes base + lane*16
  __builtin_amdgcn_global_load_lds((g_u32*)g, (l_u32*)l, 16, 0, 0);
}

// ---- fused preprocess: blocks [0,2048): K cvt+scale; [2048,3072): V transpose ----
__global__ __launch_bounds__(256)
void prep_kernel(const float* __restrict__ K, const float* __restrict__ V,
                 unsigned short* __restrict__ Kb, unsigned short* __restrict__ Vt,
                 float scale) {
  const int bx = blockIdx.x, tid = threadIdx.x;
  if (bx < 2048) {
    size_t idx = (size_t)bx * 256 + tid;
    const float4* kf = (const float4*)K;
    float4 a = kf[idx * 2], c = kf[idx * 2 + 1];
    uint4 o;
    o.x = pk2(a.x * scale, a.y * scale);
    o.y = pk2(a.z * scale, a.w * scale);
    o.z = pk2(c.x * scale, c.y * scale);
    o.w = pk2(c.z * scale, c.w * scale);
    ((uint4*)Kb)[idx] = o;
  } else {
    __shared__ float tile[128][33];
    const int vb = bx - 2048;                 // 1024 blocks
    const int b = vb >> 6, r = vb & 63;
    const int m0 = (r & 15) * 128, d0 = (r >> 4) * 32;
    const int c = tid & 7, mr = tid >> 3;
    const float* src = V + ((size_t)(b * SEQ) + m0) * DIM + d0;
#pragma unroll
    for (int it = 0; it < 4; ++it) {
      int m = it * 32 + mr;
      float4 x = *(const float4*)(src + (size_t)m * DIM + c * 4);
      tile[m][c * 4 + 0] = x.x; tile[m][c * 4 + 1] = x.y;
      tile[m][c * 4 + 2] = x.z; tile[m][c * 4 + 3] = x.w;
    }
    __syncthreads();
    const int dr = tid >> 3, s = tid & 7;
    unsigned short* dst = Vt + ((size_t)(b * DIM) + d0 + dr) * SEQ + m0;
#pragma unroll
    for (int it = 0; it < 2; ++it) {
      int slot = it * 8 + s;
      uint4 o;
      o.x = pk2(tile[slot * 8 + 0][dr], tile[slot * 8 + 1][dr]);
      o.y = pk2(tile[slot * 8 + 2][dr], tile[slot * 8 + 3][dr]);
      o.z = pk2(tile[slot * 8 + 4][dr], tile[slot * 8 + 5][dr]);
      o.w = pk2(tile[slot * 8 + 6][dr], tile[slot * 8 + 7][dr]);
      *(uint4*)(dst + slot * 8) = o;
    }
  }
}

// ---- main flash attention ----
// LDS: 4 wave-private slices of 16KB at smem + wv*16384:
//   K slice [32 rows][256B], [r][x] holds K[T*128 + wv*32 + r][x ^ ((r&15)<<4)]
//   V slice @+8192B: [128 dv][64B], [dv][x] holds Vt[dv][T*128+wv*32 + (x^((dv&3)<<4))/2]
// Epilogue: partial O [wv][32 q][128 dv] f32 = 16KB at the SAME slice (private
// write), lsum f32[4][32] @65536. Total 66560B -> 2 blocks/CU.

__global__ __launch_bounds__(256, 2)
void attn_kernel(const float* __restrict__ Qf,
                 const unsigned short* __restrict__ Kb,
                 const unsigned short* __restrict__ Vtb,
                 float* __restrict__ out) {
  __shared__ __align__(1024) unsigned char smem[66560];
  unsigned short* sm16 = (unsigned short*)smem;

  const int tid  = threadIdx.x;
  const int wv   = tid >> 6;                // = w_m (4-way m-split)
  const int lane = tid & 63;
  const int l31  = lane & 31;
  const int q2   = lane >> 5;

  // XCD-aware swizzle: 1024 blocks, xcd = bid%8 gets contiguous work chunk
  // (bijective: 1024 % 8 == 0). Work w = batch*64 + qchunk.
  const int f  = blockIdx.x;
  const int w  = ((f & 7) << 7) + (f >> 3);
  const int b  = w >> 6;
  const int q0 = (w & 63) << 5;             // 32 q-rows per block

  const unsigned short* kb = Kb  + (size_t)b * SEQ * DIM;   // [m][d], pre-scaled
  const unsigned short* vb = Vtb + (size_t)b * SEQ * DIM;   // [dv][m]

  // Q fragments (B-operand of swapped QK^T): lane (l31,q2) holds Q[q0+l31][c*16+q2*8+j]
  bf16x8 aq[8];
  {
    const float* qp = Qf + ((size_t)(b * SEQ) + q0 + l31) * DIM + q2 * 8;
#pragma unroll
    for (int c = 0; c < 8; ++c) {
      float4 x = *(const float4*)(qp + c * 16);
      float4 y = *(const float4*)(qp + c * 16 + 4);
      union { unsigned i[4]; bf16x8 v; } u;
      u.i[0] = pk2(x.x, x.y); u.i[1] = pk2(x.z, x.w);
      u.i[2] = pk2(y.x, y.y); u.i[3] = pk2(y.z, y.w);
      aq[c] = u.v;
    }
  }

  // DMA source offsets (ushort units, within one tile's span), pre-swizzled so
  // linear LDS dest + swizzled read = correct element.
  unsigned koff[8], voff[8];
#pragma unroll
  for (int i = 0; i < 8; ++i) {
    int r = i * 4 + (lane >> 4);            // K slice row 0..31 (local)
    koff[i] = (unsigned)((wv * 32 + r) * 128 + (((lane & 15) ^ (r & 15)) << 3));
    int dv = i * 16 + (lane >> 2);          // V slice row = dv 0..127
    voff[i] = (unsigned)(dv * 2048 + wv * 32 + (((lane & 3) ^ (dv & 3)) << 3));
  }
  unsigned short* kd = sm16 + wv * 8192;          // K slice dest (ushort)
  unsigned short* vd = sm16 + wv * 8192 + 4096;   // V slice dest
  const unsigned char* kS = smem + wv * 16384;    // K slice (bytes)
  const unsigned char* vS = smem + wv * 16384 + 8192;

#define STAGE_K(TK) do {                                                     \
    const unsigned short* s_ = kb + ((size_t)(TK) << 14);                    \
    _Pragma("unroll")                                                        \
    for (int i = 0; i < 8; ++i) gl2lds16(s_ + koff[i], kd + i * 512);        \
  } while (0)
#define STAGE_V(TK) do {                                                     \
    const unsigned short* s_ = vb + ((TK) << 7);                             \
    _Pragma("unroll")                                                        \
    for (int i = 0; i < 8; ++i) gl2lds16(s_ + voff[i], vd + i * 512);        \
  } while (0)

  f32x16 oacc[4];
#pragma unroll
  for (int t = 0; t < 4; ++t)
#pragma unroll
    for (int i = 0; i < 16; ++i) oacc[t][i] = 0.0f;
  float ls[4] = {0.0f, 0.0f, 0.0f, 0.0f};

  STAGE_K(0);
  STAGE_V(0);

#pragma unroll 1
  for (int kt = 0; kt < NT; ++kt) {
    // my K(kt), V(kt) landed (private DMA; no cross-wave dependency)
    asm volatile("s_waitcnt vmcnt(0)" ::: "memory");
    __builtin_amdgcn_sched_barrier(0);

    // K slice -> regs, then free the slice and restage K(kt+1)
    bf16x8 kf[8];
#pragma unroll
    for (int c = 0; c < 8; ++c)
      kf[c] = *(const bf16x8*)(kS + l31 * 256 + ((((c << 1) + q2) ^ (l31 & 15)) << 4));
    asm volatile("s_waitcnt lgkmcnt(0)" ::: "memory");
    __builtin_amdgcn_sched_barrier(0);
    if (kt + 1 < NT) STAGE_K(kt + 1);

    // S^T = K . Q^T : two independent 4-deep MFMA chains (pure-reg operands)
    f32x16 se, so;
#pragma unroll
    for (int i = 0; i < 16; ++i) { se[i] = 0.0f; so[i] = 0.0f; }
    __builtin_amdgcn_s_setprio(1);
#pragma unroll
    for (int c = 0; c < 4; ++c) {
      se = __builtin_amdgcn_mfma_f32_32x32x16_bf16(kf[2 * c],     aq[2 * c],     se, 0, 0, 0);
      so = __builtin_amdgcn_mfma_f32_32x32x16_bf16(kf[2 * c + 1], aq[2 * c + 1], so, 0, 0, 0);
    }
    __builtin_amdgcn_s_setprio(0);

    // P = exp2(S); partial row sums (this wave's 32-m quarter)
    float p[16];
#pragma unroll
    for (int i = 0; i < 16; ++i) p[i] = fast_exp2(se[i] + so[i]);
#pragma unroll
    for (int i = 0; i < 4; ++i) {
      ls[0] += p[4 * i + 0]; ls[1] += p[4 * i + 1];
      ls[2] += p[4 * i + 2]; ls[3] += p[4 * i + 3];
    }

    // P -> PV A-fragments in-register: cvt_pk pairs + permlane32_swap
    unsigned d0, d1, d2, d3, d4, d5, d6, d7;
    asm("v_cvt_pk_bf16_f32 %0, %1, %2" : "=v"(d0) : "v"(p[0]),  "v"(p[1]));
    asm("v_cvt_pk_bf16_f32 %0, %1, %2" : "=v"(d1) : "v"(p[2]),  "v"(p[3]));
    asm("v_cvt_pk_bf16_f32 %0, %1, %2" : "=v"(d2) : "v"(p[4]),  "v"(p[5]));
    asm("v_cvt_pk_bf16_f32 %0, %1, %2" : "=v"(d3) : "v"(p[6]),  "v"(p[7]));
    asm("v_cvt_pk_bf16_f32 %0, %1, %2" : "=v"(d4) : "v"(p[8]),  "v"(p[9]));
    asm("v_cvt_pk_bf16_f32 %0, %1, %2" : "=v"(d5) : "v"(p[10]), "v"(p[11]));
    asm("v_cvt_pk_bf16_f32 %0, %1, %2" : "=v"(d6) : "v"(p[12]), "v"(p[13]));
    asm("v_cvt_pk_bf16_f32 %0, %1, %2" : "=v"(d7) : "v"(p[14]), "v"(p[15]));
    asm("v_permlane32_swap_b32 %0, %1" : "+v"(d0), "+v"(d2));
    asm("v_permlane32_swap_b32 %0, %1" : "+v"(d1), "+v"(d3));
    asm("v_permlane32_swap_b32 %0, %1" : "+v"(d4), "+v"(d6));
    asm("v_permlane32_swap_b32 %0, %1" : "+v"(d5), "+v"(d7));
    union { unsigned u[4]; bf16x8 v; } pu0, pu1;
    pu0.u[0] = d0; pu0.u[1] = d1; pu0.u[2] = d2; pu0.u[3] = d3;
    pu1.u[0] = d4; pu1.u[1] = d5; pu1.u[2] = d6; pu1.u[3] = d7;

    // O += P . V over this wave's m-quarter (direct ds_read from private slice)
    __builtin_amdgcn_s_setprio(1);
#pragma unroll
    for (int t = 0; t < 4; ++t) {
      int row = t * 32 + l31;
      bf16x8 bv0 = *(const bf16x8*)(vS + row * 64 + (((q2 << 4)) ^ ((row & 3) << 4)));
      oacc[t] = __builtin_amdgcn_mfma_f32_32x32x16_bf16(pu0.v, bv0, oacc[t], 0, 0, 0);
      bf16x8 bv1 = *(const bf16x8*)(vS + row * 64 + ((32 + (q2 << 4)) ^ ((row & 3) << 4)));
      oacc[t] = __builtin_amdgcn_mfma_f32_32x32x16_bf16(pu1.v, bv1, oacc[t], 0, 0, 0);
    }
    __builtin_amdgcn_s_setprio(0);

    // V reads retired -> slice free; restage V(kt+1)
    asm volatile("s_waitcnt lgkmcnt(0)" ::: "memory");
    __builtin_amdgcn_sched_barrier(0);
    if (kt + 1 < NT) STAGE_V(kt + 1);
  }
#undef STAGE_K
#undef STAGE_V

  // partial row sum over this wave's m-quarter: merge q2 halves
  float lsum = (ls[0] + ls[1]) + (ls[2] + ls[3]);
  lsum += __shfl_xor(lsum, 32, 64);

  // ---- epilogue: 4-way merge of m-quarter partials ----
  // write partial O into OWN slice (private, no sync needed), layout [32q][128dv]
  float* myp = (float*)(smem + wv * 16384);
#pragma unroll
  for (int t = 0; t < 4; ++t)
#pragma unroll
    for (int r = 0; r < 16; ++r) {
      int qr = (r & 3) + ((r >> 2) << 3) + (q2 << 2);
      myp[qr * 128 + t * 32 + l31] = oacc[t][r];
    }
  float* lsumL = (float*)(smem + 65536);    // [4][32]
  if (q2 == 0) lsumL[wv * 32 + l31] = lsum;
  __syncthreads();

  // each wave reduces 8 q-rows across the 4 slices, normalizes, stores
  const float* ob = out + ((size_t)(b * SEQ) + q0) * DIM;
#pragma unroll
  for (int pass = 0; pass < 2; ++pass) {
    int q = wv * 8 + pass * 4 + (lane >> 4);
    float linv = 1.0f / (lsumL[q] + lsumL[32 + q] + lsumL[64 + q] + lsumL[96 + q]);
#pragma unroll
    for (int half = 0; half < 2; ++half) {
      int d4 = (lane & 15) + half * 16;     // float4 index within the row
      float4 v = *(const float4*)(smem + q * 512 + d4 * 16);
      float4 v1 = *(const float4*)(smem + 16384 + q * 512 + d4 * 16);
      float4 v2 = *(const float4*)(smem + 32768 + q * 512 + d4 * 16);
      float4 v3 = *(const float4*)(smem + 49152 + q * 512 + d4 * 16);
      v.x = (v.x + v1.x + v2.x + v3.x) * linv;
      v.y = (v.y + v1.y + v2.y + v3.y) * linv;
      v.z = (v.z + v1.z + v2.z + v3.z) * linv;
      v.w = (v.w + v1.w + v2.w + v3.w) * linv;
      *(float4*)((float*)ob + (size_t)q * DIM + d4 * 4) = v;
    }
  }
}

extern "C" void kernel_launch(void* const* d_in, const int* in_sizes, int n_in,
                              void* d_out, int out_size, void* d_ws, size_t ws_size,
                              hipStream_t stream) {
  const float* Q = (const float*)d_in[0];
  const float* K = (const float*)d_in[1];
  const float* V = (const float*)d_in[2];
  float* out = (float*)d_out;

  const size_t elems = (size_t)BATCH * SEQ * DIM;   // 4,194,304
  unsigned short* Kb = (unsigned short*)d_ws;       // 8 MB
  unsigned short* Vt = Kb + elems;                  // 8 MB (ws >= 16 MB)

  const double TEMPERATURE = 11.313708498984761;
  const float scale = (float)(1.4426950408889634 / TEMPERATURE);  // log2(e)/temp on K

  prep_kernel<<<3072, 256, 0, stream>>>(K, V, Kb, Vt, scale);
  attn_kernel<<<1024, 256, 0, stream>>>(Q, Kb, Vt, out);
}

// Round 8
// 133.884 us; speedup vs baseline: 1.2270x; 1.1140x over previous
//
#include <hip/hip_runtime.h>

// b=16, n=m=2048, d=dv=128, fp32 in/out, temp=sqrt(128).
// Prep: K -> bf16 scaled by log2e/temp; V -> Vt[b][dv][m] bf16. Q cast in-kernel.
// Attention: swapped S^T = K.Q^T via 32x32x16 bf16 MFMA, P = exp2(S),
// P->A-frag via v_cvt_pk_bf16_f32 + v_permlane32_swap_b32, PV accumulate.
// K/V staged by global_load_lds (linear LDS dest, XOR-swizzled global source).
// Round-8: ONE barrier per tile. Stages moved to the TOP of the body (right
// after the barrier), so at bar(t) the tiles being opened were staged a full
// body (~800cy) earlier and a single counted vmcnt(4) covers BOTH K(t) and
// V(t) landing. R4's bar2 deleted (32 fewer convoys/block + one fewer wait
// point). Overwrite safety without bar2: a wave past bar(t) already ISSUED
// body t-1's QK/PV MFMAs, whose LDS operand reads completed before issue
// (compiler lgkm discipline) -> vbuf[(t+1)&1] (last read: PV(t-1)) and
// kbuf[(t+2)%3] (last read: QK(t-1)) are free. Issue order V(t+1) then
// K(t+2) keeps the wait a uniform vmcnt(4). K triple-buffered, V double
// (80KB LDS -> 2 blocks/CU). Index math identical to R5 (verified).
// R7 lessons: V 64B-row slices = 4-way conflicts (6.3M); vmcnt(0) right
// after issue = zero slack. Both reverted here.
// Block = 4 waves: 2 q-waves (BQ=64) x 2 m-waves (BK=64 split 32/32).
// Grid 16x32 = 512 blocks -> 2 blocks/CU, 8 waves/CU.

#define BATCH 16
#define SEQ   2048
#define DIM   128
#define NT    (SEQ / 64)

typedef short bf16x8 __attribute__((ext_vector_type(8)));
typedef float f32x16 __attribute__((ext_vector_type(16)));

static __device__ __forceinline__ unsigned pk2(float lo, float hi) {
  union { float f; unsigned u; } a, b;
  a.f = lo; b.f = hi;
  return ((b.u + 0x8000u) & 0xffff0000u) | ((a.u + 0x8000u) >> 16);
}
static __device__ __forceinline__ float fast_exp2(float x) {
#if __has_builtin(__builtin_amdgcn_exp2f)
  return __builtin_amdgcn_exp2f(x);
#else
  return exp2f(x);
#endif
}

typedef __attribute__((address_space(1))) const unsigned int g_u32;
typedef __attribute__((address_space(3))) unsigned int l_u32;
static __device__ __forceinline__ void gl2lds16(const unsigned short* g, unsigned short* l) {
  // per-lane global src; wave-uniform LDS base, HW writes base + lane*16
  __builtin_amdgcn_global_load_lds((g_u32*)g, (l_u32*)l, 16, 0, 0);
}

// ---- fused preprocess: blocks [0,2048): K cvt+scale; [2048,3072): V transpose ----
__global__ __launch_bounds__(256)
void prep_kernel(const float* __restrict__ K, const float* __restrict__ V,
                 unsigned short* __restrict__ Kb, unsigned short* __restrict__ Vt,
                 float scale) {
  const int bx = blockIdx.x, tid = threadIdx.x;
  if (bx < 2048) {
    size_t idx = (size_t)bx * 256 + tid;
    const float4* kf = (const float4*)K;
    float4 a = kf[idx * 2], c = kf[idx * 2 + 1];
    uint4 o;
    o.x = pk2(a.x * scale, a.y * scale);
    o.y = pk2(a.z * scale, a.w * scale);
    o.z = pk2(c.x * scale, c.y * scale);
    o.w = pk2(c.z * scale, c.w * scale);
    ((uint4*)Kb)[idx] = o;
  } else {
    __shared__ float tile[128][33];
    const int vb = bx - 2048;                 // 1024 blocks
    const int b = vb >> 6, r = vb & 63;
    const int m0 = (r & 15) * 128, d0 = (r >> 4) * 32;
    const int c = tid & 7, mr = tid >> 3;
    const float* src = V + ((size_t)(b * SEQ) + m0) * DIM + d0;
#pragma unroll
    for (int it = 0; it < 4; ++it) {
      int m = it * 32 + mr;
      float4 x = *(const float4*)(src + (size_t)m * DIM + c * 4);
      tile[m][c * 4 + 0] = x.x; tile[m][c * 4 + 1] = x.y;
      tile[m][c * 4 + 2] = x.z; tile[m][c * 4 + 3] = x.w;
    }
    __syncthreads();
    const int dr = tid >> 3, s = tid & 7;
    unsigned short* dst = Vt + ((size_t)(b * DIM) + d0 + dr) * SEQ + m0;
#pragma unroll
    for (int it = 0; it < 2; ++it) {
      int slot = it * 8 + s;
      uint4 o;
      o.x = pk2(tile[slot * 8 + 0][dr], tile[slot * 8 + 1][dr]);
      o.y = pk2(tile[slot * 8 + 2][dr], tile[slot * 8 + 3][dr]);
      o.z = pk2(tile[slot * 8 + 4][dr], tile[slot * 8 + 5][dr]);
      o.w = pk2(tile[slot * 8 + 6][dr], tile[slot * 8 + 7][dr]);
      *(uint4*)(dst + slot * 8) = o;
    }
  }
}

// ---- main flash attention ----
// LDS (bytes): K bufs @0, @16384, @32768 (3x16KB); V bufs @49152, @65536 (2x16KB)
// total 81920 B. K buf: 64 rows x 256B linear, [row][x] holds
// K[m0+row][x ^ ((row&15)<<4)]. V buf: 128 rows x 128B linear, [row][x] holds
// Vt[row][m0 + (x ^ ((row&7)<<4))/2].
// Epilogue (after __syncthreads) aliases: cb f32[2][4096] @0, cbL @32768.

__global__ __launch_bounds__(256, 2)
void attn_kernel(const float* __restrict__ Qf,
                 const unsigned short* __restrict__ Kb,
                 const unsigned short* __restrict__ Vtb,
                 float* __restrict__ out) {
  __shared__ __align__(1024) unsigned char smem[81920];
  unsigned short* sm16 = (unsigned short*)smem;

  const int tid  = threadIdx.x;
  const int wv   = tid >> 6;
  const int w_q  = wv & 1;                  // q-subtile (32 rows)
  const int w_m  = wv >> 1;                 // m-half (32 cols) of the 64-tile
  const int lane = tid & 63;
  const int l31  = lane & 31;
  const int q2   = lane >> 5;
  const int b    = blockIdx.x;
  const int q0   = blockIdx.y * 64 + w_q * 32;

  const unsigned short* kb = Kb  + (size_t)b * SEQ * DIM;   // [m][d], pre-scaled
  const unsigned short* vb = Vtb + (size_t)b * SEQ * DIM;   // [dv][m]

  // Q fragments (B-operand of swapped QK^T): lane (l31,q2) holds Q[q0+l31][c*16+q2*8+j]
  bf16x8 aq[8];
  {
    const float* qp = Qf + ((size_t)(b * SEQ) + q0 + l31) * DIM + q2 * 8;
#pragma unroll
    for (int c = 0; c < 8; ++c) {
      float4 x = *(const float4*)(qp + c * 16);
      float4 y = *(const float4*)(qp + c * 16 + 4);
      union { unsigned i[4]; bf16x8 v; } u;
      u.i[0] = pk2(x.x, x.y); u.i[1] = pk2(x.z, x.w);
      u.i[2] = pk2(y.x, y.y); u.i[3] = pk2(y.z, y.w);
      aq[c] = u.v;
    }
  }

  // staging source offsets (ushort units); LDS dest linear, global src pre-swizzled
  unsigned kgo[4], vgo[4];
#pragma unroll
  for (int i = 0; i < 4; ++i) {
    int ch = wv * 4 + i;
    int krow = ch * 4 + (lane >> 4);
    kgo[i] = (unsigned)(krow * 128) + ((((lane & 15) << 4) ^ ((krow & 15) << 4)) >> 1);
    int vrow = ch * 8 + (lane >> 3);
    vgo[i] = (unsigned)(vrow * 2048) + ((((lane & 7) << 4) ^ ((vrow & 7) << 4)) >> 1);
  }

  // swizzled read base offsets (bytes, within a buffer)
  const int kro = ((w_m * 32 + l31) << 8) + ((q2 << 4) ^ ((l31 & 15) << 4));
  const int vro = (l31 << 7) + (((w_m << 6) + (q2 << 4)) ^ ((l31 & 7) << 4));

  f32x16 oacc[4];
#pragma unroll
  for (int t = 0; t < 4; ++t)
#pragma unroll
    for (int i = 0; i < 16; ++i) oacc[t][i] = 0.0f;
  float ls[4] = {0.0f, 0.0f, 0.0f, 0.0f};

#define STAGE_K(TK, KOFF) do {                                               \
    const unsigned short* kt_b = kb + ((size_t)(TK) << 13);                  \
    unsigned short* kd = sm16 + (((KOFF) + wv * 4096) >> 1);                 \
    _Pragma("unroll")                                                        \
    for (int i = 0; i < 4; ++i) gl2lds16(kt_b + kgo[i], kd + i * 512);       \
  } while (0)
#define STAGE_V(TV, VOFF) do {                                               \
    const unsigned short* vt_b = vb + ((TV) << 6);                           \
    unsigned short* vd = sm16 + (((VOFF) + wv * 4096) >> 1);                 \
    _Pragma("unroll")                                                        \
    for (int i = 0; i < 4; ++i) gl2lds16(vt_b + vgo[i], vd + i * 512);       \
  } while (0)

  // prologue: K(0), V(0), K(1)  (12 loads in flight; bar(0) drains to 4)
  STAGE_K(0, 0);
  STAGE_V(0, 49152);
  STAGE_K(1, 16384);

  int kcur = 0;        // K buf offset of tile t     (0 / 16384 / 32768)
  int kstg = 32768;    // K buf offset for tile t+2
  int vcur = 0;        // V buf sub-offset of tile t (0 / 16384), base 49152

#pragma unroll 1
  for (int kt = 0; kt < NT; ++kt) {
    // ---- single bar: K(t) AND V(t) landed for ALL waves (4 newer: K(t+2)
    // after body staging order below; at entry: V(t)+... drained to 4) ----
    asm volatile("s_waitcnt vmcnt(4)" ::: "memory");
    __builtin_amdgcn_s_barrier();
    __builtin_amdgcn_sched_barrier(0);

    // stages at body top: targets' last readers were body t-1's QK/PV, whose
    // LDS reads completed before those MFMAs issued (pre-bar). Order V then K
    // keeps bar's wait at vmcnt(4) with K(t+2) as the only flyer. Wrap indices
    // at the end are drained by the epilogue __syncthreads.
    STAGE_V((kt + 1) & (NT - 1), 49152 + (vcur ^ 16384));
    STAGE_K((kt + 2) & (NT - 1), kstg);

    const unsigned char* kB = smem + kcur;
    const unsigned char* vB = smem + 49152 + vcur;

    // S^T = K . Q^T : two independent 4-deep MFMA chains, merged at the end.
    // lane (l31,q2) holds S[q=l31][m=(r&3)+8*(r>>2)+4*q2]
    f32x16 se, so;
#pragma unroll
    for (int i = 0; i < 16; ++i) { se[i] = 0.0f; so[i] = 0.0f; }
    __builtin_amdgcn_s_setprio(1);
#pragma unroll
    for (int c = 0; c < 4; ++c) {
      bf16x8 b0 = *(const bf16x8*)(kB + (kro ^ ((2 * c) << 5)));
      se = __builtin_amdgcn_mfma_f32_32x32x16_bf16(b0, aq[2 * c], se, 0, 0, 0);
      bf16x8 b1 = *(const bf16x8*)(kB + (kro ^ ((2 * c + 1) << 5)));
      so = __builtin_amdgcn_mfma_f32_32x32x16_bf16(b1, aq[2 * c + 1], so, 0, 0, 0);
    }
    __builtin_amdgcn_s_setprio(0);

    // P = exp2(S); partial row sums in 4 independent accumulators
    float p[16];
#pragma unroll
    for (int i = 0; i < 16; ++i) p[i] = fast_exp2(se[i] + so[i]);
#pragma unroll
    for (int i = 0; i < 4; ++i) {
      ls[0] += p[4 * i + 0]; ls[1] += p[4 * i + 1];
      ls[2] += p[4 * i + 2]; ls[3] += p[4 * i + 3];
    }

    // P -> PV A-fragments fully in-register: cvt_pk pairs + permlane32_swap
    unsigned d0, d1, d2, d3, d4, d5, d6, d7;
    asm("v_cvt_pk_bf16_f32 %0, %1, %2" : "=v"(d0) : "v"(p[0]),  "v"(p[1]));
    asm("v_cvt_pk_bf16_f32 %0, %1, %2" : "=v"(d1) : "v"(p[2]),  "v"(p[3]));
    asm("v_cvt_pk_bf16_f32 %0, %1, %2" : "=v"(d2) : "v"(p[4]),  "v"(p[5]));
    asm("v_cvt_pk_bf16_f32 %0, %1, %2" : "=v"(d3) : "v"(p[6]),  "v"(p[7]));
    asm("v_cvt_pk_bf16_f32 %0, %1, %2" : "=v"(d4) : "v"(p[8]),  "v"(p[9]));
    asm("v_cvt_pk_bf16_f32 %0, %1, %2" : "=v"(d5) : "v"(p[10]), "v"(p[11]));
    asm("v_cvt_pk_bf16_f32 %0, %1, %2" : "=v"(d6) : "v"(p[12]), "v"(p[13]));
    asm("v_cvt_pk_bf16_f32 %0, %1, %2" : "=v"(d7) : "v"(p[14]), "v"(p[15]));
    asm("v_permlane32_swap_b32 %0, %1" : "+v"(d0), "+v"(d2));
    asm("v_permlane32_swap_b32 %0, %1" : "+v"(d1), "+v"(d3));
    asm("v_permlane32_swap_b32 %0, %1" : "+v"(d4), "+v"(d6));
    asm("v_permlane32_swap_b32 %0, %1" : "+v"(d5), "+v"(d7));
    union { unsigned u[4]; bf16x8 v; } pu0, pu1;
    pu0.u[0] = d0; pu0.u[1] = d1; pu0.u[2] = d2; pu0.u[3] = d3;
    pu1.u[0] = d4; pu1.u[1] = d5; pu1.u[2] = d6; pu1.u[3] = d7;

    // O += P . V over this wave's m-half (V(t) landed per this body's bar)
    __builtin_amdgcn_s_setprio(1);
#pragma unroll
    for (int t = 0; t < 4; ++t) {
      bf16x8 bv0 = *(const bf16x8*)(vB + t * 4096 + vro);
      oacc[t] = __builtin_amdgcn_mfma_f32_32x32x16_bf16(pu0.v, bv0, oacc[t], 0, 0, 0);
      bf16x8 bv1 = *(const bf16x8*)(vB + t * 4096 + (vro ^ 32));
      oacc[t] = __builtin_amdgcn_mfma_f32_32x32x16_bf16(pu1.v, bv1, oacc[t], 0, 0, 0);
    }
    __builtin_amdgcn_s_setprio(0);

    // rotate buffers
    kcur = (kcur == 32768) ? 0 : kcur + 16384;
    kstg = (kstg == 32768) ? 0 : kstg + 16384;
    vcur ^= 16384;
  }
#undef STAGE_K
#undef STAGE_V

  float lsum = (ls[0] + ls[1]) + (ls[2] + ls[3]);
  // merge q2 halves of the row sum: lane (l31,*) -> sum over this wave's 32 m
  lsum += __shfl_xor(lsum, 32, 64);

  // combine the two m-halves through LDS, normalize, coalesced store
  __syncthreads();                          // drains wrap-stage; all tile reads done
  float* cb  = (float*)smem;                // [2][64][64] partials = 32768 B
  float* cbL = (float*)(smem + 32768);      // [2][64] row sums
  if (w_m == 1) {
    float* my = cb + w_q * 4096;
#pragma unroll
    for (int t = 0; t < 4; ++t)
#pragma unroll
      for (int r = 0; r < 16; ++r)
        my[(t * 16 + r) * 64 + lane] = oacc[t][r];
  }
  cbL[w_m * 64 + w_q * 32 + l31] = lsum;    // both q2 lanes write same value
  __syncthreads();
  if (w_m == 0) {
    const float* pr = cb + w_q * 4096;
    float linv[16];
#pragma unroll
    for (int r = 0; r < 16; ++r) {
      int qr = (r & 3) + ((r >> 2) << 3) + (q2 << 2);
      linv[r] = 1.0f / (cbL[w_q * 32 + qr] + cbL[64 + w_q * 32 + qr]);
    }
    float* ob = out + ((size_t)(b * SEQ) + q0) * DIM;
#pragma unroll
    for (int t = 0; t < 4; ++t)
#pragma unroll
      for (int r = 0; r < 16; ++r) {
        int qr = (r & 3) + ((r >> 2) << 3) + (q2 << 2);
        ob[(size_t)qr * DIM + t * 32 + l31] = (oacc[t][r] + pr[(t * 16 + r) * 64 + lane]) * linv[r];
      }
  }
}

extern "C" void kernel_launch(void* const* d_in, const int* in_sizes, int n_in,
                              void* d_out, int out_size, void* d_ws, size_t ws_size,
                              hipStream_t stream) {
  const float* Q = (const float*)d_in[0];
  const float* K = (const float*)d_in[1];
  const float* V = (const float*)d_in[2];
  float* out = (float*)d_out;

  const size_t elems = (size_t)BATCH * SEQ * DIM;   // 4,194,304
  unsigned short* Kb = (unsigned short*)d_ws;       // 8 MB
  unsigned short* Vt = Kb + elems;                  // 8 MB (ws >= 16 MB)

  const double TEMPERATURE = 11.313708498984761;
  const float scale = (float)(1.4426950408889634 / TEMPERATURE);  // log2(e)/temp on K

  prep_kernel<<<3072, 256, 0, stream>>>(K, V, Kb, Vt, scale);
  attn_kernel<<<dim3(BATCH, SEQ / 64), 256, 0, stream>>>(Q, Kb, Vt, out);
}

// Round 9
// 133.157 us; speedup vs baseline: 1.2337x; 1.0055x over previous
//
#include <hip/hip_runtime.h>

// b=16, n=m=2048, d=dv=128, fp32 in/out, temp=sqrt(128).
// Prep: K -> bf16 scaled by log2e/temp; V -> Vt[b][dv][m] bf16. Q cast in-kernel.
// Attention: swapped S^T = K.Q^T via 32x32x16 bf16 MFMA, P = exp2(S),
// P->A-frag via v_cvt_pk_bf16_f32 + v_permlane32_swap_b32, PV accumulate.
// Round-9: CROSS-BODY PIPELINE. Body t = { bar ; STAGE_V(t+1) ; STAGE_K(t+3) ;
// QK(t+1) ; PV(t) ; SM(t+1)->pu }. Only pu (8 VGPR) crosses the boundary
// (R2's pipeline carried vr[8]+dual-S and spilled; this doesn't). Each
// bar-interval now has 16 MFMAs in 6 independent chains (QK 8-chain +
// 4x oacc 2-chains) -> QK's dependent latency is filled by PV's independent
// MFMAs; SM's exp2 stretch overlaps the other wave's MFMA stretch. se/so
// split dropped (PV provides the ILP now): -16 VALU adds, -16 VGPR.
// Sync: ONE bar/tile, vmcnt(4). Stage set {V(t+1), K(t+3)} gives drain set
// {K(t+1), V(t)} at bar(t) by induction (leftover = K(t+2) only):
//   after bar(t-1): {K(t+1)} ; +V(t),K(t+2) ; bar(t) vmcnt(4) drains
//   K(t+1),V(t) ; leaves {K(t+2)}.  K: 2-body slack, V: 1-body (proven).
// K triple-buffered, V double (80KB -> 2 blocks/CU). Overwrite safety:
// stage targets' last readers ran pre-bar (MFMA issue implies operand
// ds_reads completed). Layouts/indices byte-identical to R5.
// Block = 4 waves: 2 q-waves (BQ=64) x 2 m-waves (BK=64 split 32/32).
// Grid 16x32 = 512 blocks -> 2 blocks/CU, 8 waves/CU.

#define BATCH 16
#define SEQ   2048
#define DIM   128
#define NT    (SEQ / 64)

typedef short bf16x8 __attribute__((ext_vector_type(8)));
typedef float f32x16 __attribute__((ext_vector_type(16)));

static __device__ __forceinline__ unsigned pk2(float lo, float hi) {
  union { float f; unsigned u; } a, b;
  a.f = lo; b.f = hi;
  return ((b.u + 0x8000u) & 0xffff0000u) | ((a.u + 0x8000u) >> 16);
}
static __device__ __forceinline__ float fast_exp2(float x) {
#if __has_builtin(__builtin_amdgcn_exp2f)
  return __builtin_amdgcn_exp2f(x);
#else
  return exp2f(x);
#endif
}

typedef __attribute__((address_space(1))) const unsigned int g_u32;
typedef __attribute__((address_space(3))) unsigned int l_u32;
static __device__ __forceinline__ void gl2lds16(const unsigned short* g, unsigned short* l) {
  // per-lane global src; wave-uniform LDS base, HW writes base + lane*16
  __builtin_amdgcn_global_load_lds((g_u32*)g, (l_u32*)l, 16, 0, 0);
}

// ---- fused preprocess: blocks [0,2048): K cvt+scale; [2048,3072): V transpose ----
__global__ __launch_bounds__(256)
void prep_kernel(const float* __restrict__ K, const float* __restrict__ V,
                 unsigned short* __restrict__ Kb, unsigned short* __restrict__ Vt,
                 float scale) {
  const int bx = blockIdx.x, tid = threadIdx.x;
  if (bx < 2048) {
    size_t idx = (size_t)bx * 256 + tid;
    const float4* kf = (const float4*)K;
    float4 a = kf[idx * 2], c = kf[idx * 2 + 1];
    uint4 o;
    o.x = pk2(a.x * scale, a.y * scale);
    o.y = pk2(a.z * scale, a.w * scale);
    o.z = pk2(c.x * scale, c.y * scale);
    o.w = pk2(c.z * scale, c.w * scale);
    ((uint4*)Kb)[idx] = o;
  } else {
    __shared__ float tile[128][33];
    const int vb = bx - 2048;                 // 1024 blocks
    const int b = vb >> 6, r = vb & 63;
    const int m0 = (r & 15) * 128, d0 = (r >> 4) * 32;
    const int c = tid & 7, mr = tid >> 3;
    const float* src = V + ((size_t)(b * SEQ) + m0) * DIM + d0;
#pragma unroll
    for (int it = 0; it < 4; ++it) {
      int m = it * 32 + mr;
      float4 x = *(const float4*)(src + (size_t)m * DIM + c * 4);
      tile[m][c * 4 + 0] = x.x; tile[m][c * 4 + 1] = x.y;
      tile[m][c * 4 + 2] = x.z; tile[m][c * 4 + 3] = x.w;
    }
    __syncthreads();
    const int dr = tid >> 3, s = tid & 7;
    unsigned short* dst = Vt + ((size_t)(b * DIM) + d0 + dr) * SEQ + m0;
#pragma unroll
    for (int it = 0; it < 2; ++it) {
      int slot = it * 8 + s;
      uint4 o;
      o.x = pk2(tile[slot * 8 + 0][dr], tile[slot * 8 + 1][dr]);
      o.y = pk2(tile[slot * 8 + 2][dr], tile[slot * 8 + 3][dr]);
      o.z = pk2(tile[slot * 8 + 4][dr], tile[slot * 8 + 5][dr]);
      o.w = pk2(tile[slot * 8 + 6][dr], tile[slot * 8 + 7][dr]);
      *(uint4*)(dst + slot * 8) = o;
    }
  }
}

// ---- main flash attention ----
// LDS (bytes): K bufs @0, @16384, @32768 (3x16KB); V bufs @49152, @65536 (2x16KB)
// total 81920 B. K buf: 64 rows x 256B linear, [row][x] holds
// K[m0+row][x ^ ((row&15)<<4)]. V buf: 128 rows x 128B linear, [row][x] holds
// Vt[row][m0 + (x ^ ((row&7)<<4))/2].
// Epilogue (after __syncthreads) aliases: cb f32[2][4096] @0, cbL @32768.

__global__ __launch_bounds__(256, 2)
void attn_kernel(const float* __restrict__ Qf,
                 const unsigned short* __restrict__ Kb,
                 const unsigned short* __restrict__ Vtb,
                 float* __restrict__ out) {
  __shared__ __align__(1024) unsigned char smem[81920];
  unsigned short* sm16 = (unsigned short*)smem;

  const int tid  = threadIdx.x;
  const int wv   = tid >> 6;
  const int w_q  = wv & 1;                  // q-subtile (32 rows)
  const int w_m  = wv >> 1;                 // m-half (32 cols) of the 64-tile
  const int lane = tid & 63;
  const int l31  = lane & 31;
  const int q2   = lane >> 5;
  const int b    = blockIdx.x;
  const int q0   = blockIdx.y * 64 + w_q * 32;

  const unsigned short* kb = Kb  + (size_t)b * SEQ * DIM;   // [m][d], pre-scaled
  const unsigned short* vb = Vtb + (size_t)b * SEQ * DIM;   // [dv][m]

  // Q fragments (B-operand of swapped QK^T): lane (l31,q2) holds Q[q0+l31][c*16+q2*8+j]
  bf16x8 aq[8];
  {
    const float* qp = Qf + ((size_t)(b * SEQ) + q0 + l31) * DIM + q2 * 8;
#pragma unroll
    for (int c = 0; c < 8; ++c) {
      float4 x = *(const float4*)(qp + c * 16);
      float4 y = *(const float4*)(qp + c * 16 + 4);
      union { unsigned i[4]; bf16x8 v; } u;
      u.i[0] = pk2(x.x, x.y); u.i[1] = pk2(x.z, x.w);
      u.i[2] = pk2(y.x, y.y); u.i[3] = pk2(y.z, y.w);
      aq[c] = u.v;
    }
  }

  // staging source offsets (ushort units); LDS dest linear, global src pre-swizzled
  unsigned kgo[4], vgo[4];
#pragma unroll
  for (int i = 0; i < 4; ++i) {
    int ch = wv * 4 + i;
    int krow = ch * 4 + (lane >> 4);
    kgo[i] = (unsigned)(krow * 128) + ((((lane & 15) << 4) ^ ((krow & 15) << 4)) >> 1);
    int vrow = ch * 8 + (lane >> 3);
    vgo[i] = (unsigned)(vrow * 2048) + ((((lane & 7) << 4) ^ ((vrow & 7) << 4)) >> 1);
  }

  // swizzled read base offsets (bytes, within a buffer)
  const int kro = ((w_m * 32 + l31) << 8) + ((q2 << 4) ^ ((l31 & 15) << 4));
  const int vro = (l31 << 7) + (((w_m << 6) + (q2 << 4)) ^ ((l31 & 7) << 4));

  f32x16 oacc[4];
#pragma unroll
  for (int t = 0; t < 4; ++t)
#pragma unroll
    for (int i = 0; i < 16; ++i) oacc[t][i] = 0.0f;
  float ls[4] = {0.0f, 0.0f, 0.0f, 0.0f};

#define STAGE_K(TK, KOFF) do {                                               \
    const unsigned short* kt_b = kb + ((size_t)(TK) << 13);                  \
    unsigned short* kd = sm16 + (((KOFF) + wv * 4096) >> 1);                 \
    _Pragma("unroll")                                                        \
    for (int i = 0; i < 4; ++i) gl2lds16(kt_b + kgo[i], kd + i * 512);       \
  } while (0)
#define STAGE_V(TV, VOFF) do {                                               \
    const unsigned short* vt_b = vb + ((TV) << 6);                           \
    unsigned short* vd = sm16 + (((VOFF) + wv * 4096) >> 1);                 \
    _Pragma("unroll")                                                        \
    for (int i = 0; i < 4; ++i) gl2lds16(vt_b + vgo[i], vd + i * 512);       \
  } while (0)

  // QK: single 8-deep MFMA chain into S (PV supplies the ILP now)
#define QK(KOFF) do {                                                        \
    const unsigned char* kB_ = smem + (KOFF);                                \
    _Pragma("unroll")                                                        \
    for (int i = 0; i < 16; ++i) s[i] = 0.0f;                                \
    _Pragma("unroll")                                                        \
    for (int c = 0; c < 8; ++c) {                                            \
      bf16x8 bk = *(const bf16x8*)(kB_ + (kro ^ (c << 5)));                  \
      s = __builtin_amdgcn_mfma_f32_32x32x16_bf16(bk, aq[c], s, 0, 0, 0);    \
    }                                                                        \
  } while (0)

#define PV(VOFF) do {                                                        \
    const unsigned char* vB_ = smem + (VOFF);                                \
    _Pragma("unroll")                                                        \
    for (int t = 0; t < 4; ++t) {                                            \
      bf16x8 bv0 = *(const bf16x8*)(vB_ + t * 4096 + vro);                   \
      oacc[t] = __builtin_amdgcn_mfma_f32_32x32x16_bf16(pu0.v, bv0, oacc[t], 0, 0, 0); \
      bf16x8 bv1 = *(const bf16x8*)(vB_ + t * 4096 + (vro ^ 32));            \
      oacc[t] = __builtin_amdgcn_mfma_f32_32x32x16_bf16(pu1.v, bv1, oacc[t], 0, 0, 0); \
    }                                                                        \
  } while (0)

#define SM() do {                                                            \
    float p[16];                                                             \
    _Pragma("unroll")                                                        \
    for (int i = 0; i < 16; ++i) p[i] = fast_exp2(s[i]);                     \
    _Pragma("unroll")                                                        \
    for (int i = 0; i < 4; ++i) {                                            \
      ls[0] += p[4 * i + 0]; ls[1] += p[4 * i + 1];                          \
      ls[2] += p[4 * i + 2]; ls[3] += p[4 * i + 3];                          \
    }                                                                        \
    unsigned d0, d1, d2, d3, d4, d5, d6, d7;                                 \
    asm("v_cvt_pk_bf16_f32 %0, %1, %2" : "=v"(d0) : "v"(p[0]),  "v"(p[1]));  \
    asm("v_cvt_pk_bf16_f32 %0, %1, %2" : "=v"(d1) : "v"(p[2]),  "v"(p[3]));  \
    asm("v_cvt_pk_bf16_f32 %0, %1, %2" : "=v"(d2) : "v"(p[4]),  "v"(p[5]));  \
    asm("v_cvt_pk_bf16_f32 %0, %1, %2" : "=v"(d3) : "v"(p[6]),  "v"(p[7]));  \
    asm("v_cvt_pk_bf16_f32 %0, %1, %2" : "=v"(d4) : "v"(p[8]),  "v"(p[9]));  \
    asm("v_cvt_pk_bf16_f32 %0, %1, %2" : "=v"(d5) : "v"(p[10]), "v"(p[11])); \
    asm("v_cvt_pk_bf16_f32 %0, %1, %2" : "=v"(d6) : "v"(p[12]), "v"(p[13])); \
    asm("v_cvt_pk_bf16_f32 %0, %1, %2" : "=v"(d7) : "v"(p[14]), "v"(p[15])); \
    asm("v_permlane32_swap_b32 %0, %1" : "+v"(d0), "+v"(d2));                \
    asm("v_permlane32_swap_b32 %0, %1" : "+v"(d1), "+v"(d3));                \
    asm("v_permlane32_swap_b32 %0, %1" : "+v"(d4), "+v"(d6));                \
    asm("v_permlane32_swap_b32 %0, %1" : "+v"(d5), "+v"(d7));                \
    pu0.u[0] = d0; pu0.u[1] = d1; pu0.u[2] = d2; pu0.u[3] = d3;              \
    pu1.u[0] = d4; pu1.u[1] = d5; pu1.u[2] = d6; pu1.u[3] = d7;              \
  } while (0)

  f32x16 s;
  union { unsigned u[4]; bf16x8 v; } pu0, pu1;   // pipeline register (crosses bodies)

  // ---- prologue ----
  STAGE_K(0, 0);                             // K(0) -> kbuf0
  asm volatile("s_waitcnt vmcnt(0)" ::: "memory");
  __builtin_amdgcn_s_barrier();              // K(0) landed for all waves
  __builtin_amdgcn_sched_barrier(0);
  STAGE_V(0, 49152);                         // V(0) -> vbuf0   (oldest)
  STAGE_K(1, 16384);                         // K(1) -> kbuf1
  STAGE_K(2, 32768);                         // K(2) -> kbuf2   (newest: stays flying at bar(0))
  QK(0);                                     // from kbuf0
  SM();                                      // -> pu(0)

  int kread = 16384;   // kbuf of QK(t+1): (t+1)%3
  int kwrit = 0;       // kbuf of STAGE_K(t+3): t%3

#pragma unroll 1
  for (int kt = 0; kt < NT - 1; ++kt) {
    // bar(t): drains {K(t+1), V(t)} (oldest 8 of 12), leaves {K(t+2)} flying
    asm volatile("s_waitcnt vmcnt(4)" ::: "memory");
    __builtin_amdgcn_s_barrier();
    __builtin_amdgcn_sched_barrier(0);

    const int vread = 49152 + ((kt & 1) << 14);
    STAGE_V(kt + 1, 49152 + (((kt + 1) & 1) << 14));
    STAGE_K((kt + 3) & (NT - 1), kwrit);

    __builtin_amdgcn_s_setprio(1);
    QK(kread);                               // S(t+1): 8-chain on K(t+1)
    PV(vread);                               // O += P(t).V(t): 4x2 indep chains
    __builtin_amdgcn_s_setprio(0);
    SM();                                    // -> pu(t+1)

    kread = (kread == 32768) ? 0 : kread + 16384;
    kwrit = (kwrit == 32768) ? 0 : kwrit + 16384;
  }

  // tail: PV(NT-1). bar drains {K(wrap), V(NT-1)}.
  asm volatile("s_waitcnt vmcnt(4)" ::: "memory");
  __builtin_amdgcn_s_barrier();
  __builtin_amdgcn_sched_barrier(0);
  PV(49152 + (((NT - 1) & 1) << 14));

#undef STAGE_K
#undef STAGE_V
#undef QK
#undef PV
#undef SM

  float lsum = (ls[0] + ls[1]) + (ls[2] + ls[3]);
  // merge q2 halves of the row sum: lane (l31,*) -> sum over this wave's 32 m
  lsum += __shfl_xor(lsum, 32, 64);

  // combine the two m-halves through LDS, normalize, coalesced store
  __syncthreads();                          // drains wrap-stage; all tile reads done
  float* cb  = (float*)smem;                // [2][64][64] partials = 32768 B
  float* cbL = (float*)(smem + 32768);      // [2][64] row sums
  if (w_m == 1) {
    float* my = cb + w_q * 4096;
#pragma unroll
    for (int t = 0; t < 4; ++t)
#pragma unroll
      for (int r = 0; r < 16; ++r)
        my[(t * 16 + r) * 64 + lane] = oacc[t][r];
  }
  cbL[w_m * 64 + w_q * 32 + l31] = lsum;    // both q2 lanes write same value
  __syncthreads();
  if (w_m == 0) {
    const float* pr = cb + w_q * 4096;
    float linv[16];
#pragma unroll
    for (int r = 0; r < 16; ++r) {
      int qr = (r & 3) + ((r >> 2) << 3) + (q2 << 2);
      linv[r] = 1.0f / (cbL[w_q * 32 + qr] + cbL[64 + w_q * 32 + qr]);
    }
    float* ob = out + ((size_t)(b * SEQ) + q0) * DIM;
#pragma unroll
    for (int t = 0; t < 4; ++t)
#pragma unroll
      for (int r = 0; r < 16; ++r) {
        int qr = (r & 3) + ((r >> 2) << 3) + (q2 << 2);
        ob[(size_t)qr * DIM + t * 32 + l31] = (oacc[t][r] + pr[(t * 16 + r) * 64 + lane]) * linv[r];
      }
  }
}

extern "C" void kernel_launch(void* const* d_in, const int* in_sizes, int n_in,
                              void* d_out, int out_size, void* d_ws, size_t ws_size,
                              hipStream_t stream) {
  const float* Q = (const float*)d_in[0];
  const float* K = (const float*)d_in[1];
  const float* V = (const float*)d_in[2];
  float* out = (float*)d_out;

  const size_t elems = (size_t)BATCH * SEQ * DIM;   // 4,194,304
  unsigned short* Kb = (unsigned short*)d_ws;       // 8 MB
  unsigned short* Vt = Kb + elems;                  // 8 MB (ws >= 16 MB)

  const double TEMPERATURE = 11.313708498984761;
  const float scale = (float)(1.4426950408889634 / TEMPERATURE);  // log2(e)/temp on K

  prep_kernel<<<3072, 256, 0, stream>>>(K, V, Kb, Vt, scale);
  attn_kernel<<<dim3(BATCH, SEQ / 64), 256, 0, stream>>>(Q, Kb, Vt, out);
}

// Round 10
// 131.049 us; speedup vs baseline: 1.2535x; 1.0161x over previous
//
#include <hip/hip_runtime.h>

// b=16, n=m=2048, d=dv=128, fp32 in/out, temp=sqrt(128).
// Prep: K -> bf16 scaled by log2e/temp; V -> Vt[b][dv][m] bf16. Q cast in-kernel.
// Attention: swapped S^T = K.Q^T via 32x32x16 bf16 MFMA, P = exp2(S),
// P->A-frag via v_cvt_pk_bf16_f32 + v_permlane32_swap_b32, PV accumulate.
// K/V staged by global_load_lds (linear LDS dest, XOR-swizzled global source).
// Round-10: 8-WAVE CONSOLIDATION of the best (R4) schedule. Block = 512 thr =
// 4 q-subtiles x 2 m-halves (BQ=128); grid 16x16=256 -> 1 block/CU, still
// 8 waves/CU = 2/SIMD. One K/V stream now serves 4 q-waves (was 2):
// DMA-to-LDS staging per CU per tile HALVES (64->32KB) and K/V L2 reads
// halve; MFMA/ds_read counts per wave unchanged. R4's two-bar counted-vmcnt
// schedule kept verbatim; per-wave chunk count drops 4->2 so the counts are
// bar1 vmcnt(2) [K(t) landed, V(t) flying], bar2 vmcnt(4) [V(t) landed,
// K/V(t+1) flying]. Wrap-staging keeps counts uniform; epilogue
// __syncthreads drains. R9's cross-body pipeline regressed (56.8) - reverted.
// Sync-variant history: R4 50.6 = R5 50.6 < R8 52.7 < R9 56.8.

#define BATCH 16
#define SEQ   2048
#define DIM   128
#define NT    (SEQ / 64)

typedef short bf16x8 __attribute__((ext_vector_type(8)));
typedef float f32x16 __attribute__((ext_vector_type(16)));

static __device__ __forceinline__ unsigned pk2(float lo, float hi) {
  union { float f; unsigned u; } a, b;
  a.f = lo; b.f = hi;
  return ((b.u + 0x8000u) & 0xffff0000u) | ((a.u + 0x8000u) >> 16);
}
static __device__ __forceinline__ float fast_exp2(float x) {
#if __has_builtin(__builtin_amdgcn_exp2f)
  return __builtin_amdgcn_exp2f(x);
#else
  return exp2f(x);
#endif
}

typedef __attribute__((address_space(1))) const unsigned int g_u32;
typedef __attribute__((address_space(3))) unsigned int l_u32;
static __device__ __forceinline__ void gl2lds16(const unsigned short* g, unsigned short* l) {
  // per-lane global src; wave-uniform LDS base, HW writes base + lane*16
  __builtin_amdgcn_global_load_lds((g_u32*)g, (l_u32*)l, 16, 0, 0);
}

// ---- fused preprocess: blocks [0,2048): K cvt+scale; [2048,3072): V transpose ----
__global__ __launch_bounds__(256)
void prep_kernel(const float* __restrict__ K, const float* __restrict__ V,
                 unsigned short* __restrict__ Kb, unsigned short* __restrict__ Vt,
                 float scale) {
  const int bx = blockIdx.x, tid = threadIdx.x;
  if (bx < 2048) {
    size_t idx = (size_t)bx * 256 + tid;
    const float4* kf = (const float4*)K;
    float4 a = kf[idx * 2], c = kf[idx * 2 + 1];
    uint4 o;
    o.x = pk2(a.x * scale, a.y * scale);
    o.y = pk2(a.z * scale, a.w * scale);
    o.z = pk2(c.x * scale, c.y * scale);
    o.w = pk2(c.z * scale, c.w * scale);
    ((uint4*)Kb)[idx] = o;
  } else {
    __shared__ float tile[128][33];
    const int vb = bx - 2048;                 // 1024 blocks
    const int b = vb >> 6, r = vb & 63;
    const int m0 = (r & 15) * 128, d0 = (r >> 4) * 32;
    const int c = tid & 7, mr = tid >> 3;
    const float* src = V + ((size_t)(b * SEQ) + m0) * DIM + d0;
#pragma unroll
    for (int it = 0; it < 4; ++it) {
      int m = it * 32 + mr;
      float4 x = *(const float4*)(src + (size_t)m * DIM + c * 4);
      tile[m][c * 4 + 0] = x.x; tile[m][c * 4 + 1] = x.y;
      tile[m][c * 4 + 2] = x.z; tile[m][c * 4 + 3] = x.w;
    }
    __syncthreads();
    const int dr = tid >> 3, s = tid & 7;
    unsigned short* dst = Vt + ((size_t)(b * DIM) + d0 + dr) * SEQ + m0;
#pragma unroll
    for (int it = 0; it < 2; ++it) {
      int slot = it * 8 + s;
      uint4 o;
      o.x = pk2(tile[slot * 8 + 0][dr], tile[slot * 8 + 1][dr]);
      o.y = pk2(tile[slot * 8 + 2][dr], tile[slot * 8 + 3][dr]);
      o.z = pk2(tile[slot * 8 + 4][dr], tile[slot * 8 + 5][dr]);
      o.w = pk2(tile[slot * 8 + 6][dr], tile[slot * 8 + 7][dr]);
      *(uint4*)(dst + slot * 8) = o;
    }
  }
}

// ---- main flash attention ----
// LDS (bytes): K bufs @0, @16384; V bufs @32768, @49152 (64KB main loop).
// K buf: 64 rows x 256B linear, [row][x] holds K[m0+row][x ^ ((row&15)<<4)]
// V buf: 128 rows x 128B linear, [row][x] holds Vt[row][m0 + (x ^ ((row&7)<<4))/2]
// Epilogue (after __syncthreads) aliases: cb f32[4][4096] @0 (64KB),
// cbL f32[2][128] @65536 (1KB). Total 66560 -> 1 block/CU (grid=256).

__global__ __launch_bounds__(512, 2)
void attn_kernel(const float* __restrict__ Qf,
                 const unsigned short* __restrict__ Kb,
                 const unsigned short* __restrict__ Vtb,
                 float* __restrict__ out) {
  __shared__ __align__(1024) unsigned char smem[66560];
  unsigned short* sm16 = (unsigned short*)smem;

  const int tid  = threadIdx.x;
  const int wv   = tid >> 6;                // 0..7
  const int w_q  = wv & 3;                  // q-subtile (32 rows of the 128)
  const int w_m  = wv >> 2;                 // m-half (32 cols) of the 64-tile
  const int lane = tid & 63;
  const int l31  = lane & 31;
  const int q2   = lane >> 5;
  const int b    = blockIdx.x;
  const int q0   = blockIdx.y * 128 + w_q * 32;

  const unsigned short* kb = Kb  + (size_t)b * SEQ * DIM;   // [m][d], pre-scaled
  const unsigned short* vb = Vtb + (size_t)b * SEQ * DIM;   // [dv][m]

  // Q fragments (B-operand of swapped QK^T): lane (l31,q2) holds Q[q0+l31][c*16+q2*8+j]
  bf16x8 aq[8];
  {
    const float* qp = Qf + ((size_t)(b * SEQ) + q0 + l31) * DIM + q2 * 8;
#pragma unroll
    for (int c = 0; c < 8; ++c) {
      float4 x = *(const float4*)(qp + c * 16);
      float4 y = *(const float4*)(qp + c * 16 + 4);
      union { unsigned i[4]; bf16x8 v; } u;
      u.i[0] = pk2(x.x, x.y); u.i[1] = pk2(x.z, x.w);
      u.i[2] = pk2(y.x, y.y); u.i[3] = pk2(y.z, y.w);
      aq[c] = u.v;
    }
  }

  // staging source offsets (ushort units); LDS dest linear, global src pre-swizzled.
  // 8 waves x 2 chunks cover the 16 chunks of each 16KB tile.
  unsigned kgo[2], vgo[2];
#pragma unroll
  for (int i = 0; i < 2; ++i) {
    int ch = wv * 2 + i;                    // 0..15
    int krow = ch * 4 + (lane >> 4);        // 0..63
    kgo[i] = (unsigned)(krow * 128) + ((((lane & 15) << 4) ^ ((krow & 15) << 4)) >> 1);
    int vrow = ch * 8 + (lane >> 3);        // 0..127
    vgo[i] = (unsigned)(vrow * 2048) + ((((lane & 7) << 4) ^ ((vrow & 7) << 4)) >> 1);
  }

  // swizzled read base offsets (bytes, within a buffer)
  const int kro = ((w_m * 32 + l31) << 8) + ((q2 << 4) ^ ((l31 & 15) << 4));
  const int vro = (l31 << 7) + (((w_m << 6) + (q2 << 4)) ^ ((l31 & 7) << 4));

  f32x16 oacc[4];
#pragma unroll
  for (int t = 0; t < 4; ++t)
#pragma unroll
    for (int i = 0; i < 16; ++i) oacc[t][i] = 0.0f;
  float ls[4] = {0.0f, 0.0f, 0.0f, 0.0f};

  // K chunks first, then V (vmcnt counting: oldest outstanding = K chunks).
#define STAGE(TK, BUF) do {                                                  \
    const unsigned short* kt_b = kb + ((size_t)(TK) << 13);                  \
    const unsigned short* vt_b = vb + ((TK) << 6);                           \
    unsigned short* kd = sm16 + (((BUF) + wv * 2048) >> 1);                  \
    unsigned short* vd = sm16 + ((32768 + (BUF) + wv * 2048) >> 1);          \
    _Pragma("unroll")                                                        \
    for (int i = 0; i < 2; ++i) gl2lds16(kt_b + kgo[i], kd + i * 512);       \
    _Pragma("unroll")                                                        \
    for (int i = 0; i < 2; ++i) gl2lds16(vt_b + vgo[i], vd + i * 512);       \
  } while (0)

  STAGE(0, 0);

  for (int kt = 0; kt < NT; ++kt) {
    const int cur = (kt & 1) << 14;
    // ---- bar1: K(kt) landed for ALL waves; V(kt) (2 loads) still flying ----
    asm volatile("s_waitcnt vmcnt(2)" ::: "memory");
    __builtin_amdgcn_s_barrier();
    __builtin_amdgcn_sched_barrier(0);

    const unsigned char* kB = smem + cur;
    const unsigned char* vB = smem + 32768 + cur;

    // S^T = K . Q^T : two independent 4-deep MFMA chains, merged at the end.
    // lane (l31,q2) holds S[q=l31][m=(r&3)+8*(r>>2)+4*q2]
    f32x16 se, so;
#pragma unroll
    for (int i = 0; i < 16; ++i) { se[i] = 0.0f; so[i] = 0.0f; }
    __builtin_amdgcn_s_setprio(1);
#pragma unroll
    for (int c = 0; c < 4; ++c) {
      bf16x8 b0 = *(const bf16x8*)(kB + (kro ^ ((2 * c) << 5)));
      se = __builtin_amdgcn_mfma_f32_32x32x16_bf16(b0, aq[2 * c], se, 0, 0, 0);
      bf16x8 b1 = *(const bf16x8*)(kB + (kro ^ ((2 * c + 1) << 5)));
      so = __builtin_amdgcn_mfma_f32_32x32x16_bf16(b1, aq[2 * c + 1], so, 0, 0, 0);
    }
    __builtin_amdgcn_s_setprio(0);
    __builtin_amdgcn_sched_barrier(0);

    // prefetch next tile into the other buffer; stays in flight across both
    // barriers and the next QK. Wrap keeps per-wave vmcnt counts uniform;
    // drained by the epilogue __syncthreads.
    STAGE((kt + 1) & (NT - 1), 16384 - cur);
    __builtin_amdgcn_sched_barrier(0);

    // P = exp2(S); partial row sums in 4 independent accumulators
    float p[16];
#pragma unroll
    for (int i = 0; i < 16; ++i) p[i] = fast_exp2(se[i] + so[i]);
#pragma unroll
    for (int i = 0; i < 4; ++i) {
      ls[0] += p[4 * i + 0]; ls[1] += p[4 * i + 1];
      ls[2] += p[4 * i + 2]; ls[3] += p[4 * i + 3];
    }

    // P -> PV A-fragments fully in-register: cvt_pk pairs + permlane32_swap
    unsigned d0, d1, d2, d3, d4, d5, d6, d7;
    asm("v_cvt_pk_bf16_f32 %0, %1, %2" : "=v"(d0) : "v"(p[0]),  "v"(p[1]));
    asm("v_cvt_pk_bf16_f32 %0, %1, %2" : "=v"(d1) : "v"(p[2]),  "v"(p[3]));
    asm("v_cvt_pk_bf16_f32 %0, %1, %2" : "=v"(d2) : "v"(p[4]),  "v"(p[5]));
    asm("v_cvt_pk_bf16_f32 %0, %1, %2" : "=v"(d3) : "v"(p[6]),  "v"(p[7]));
    asm("v_cvt_pk_bf16_f32 %0, %1, %2" : "=v"(d4) : "v"(p[8]),  "v"(p[9]));
    asm("v_cvt_pk_bf16_f32 %0, %1, %2" : "=v"(d5) : "v"(p[10]), "v"(p[11]));
    asm("v_cvt_pk_bf16_f32 %0, %1, %2" : "=v"(d6) : "v"(p[12]), "v"(p[13]));
    asm("v_cvt_pk_bf16_f32 %0, %1, %2" : "=v"(d7) : "v"(p[14]), "v"(p[15]));
    asm("v_permlane32_swap_b32 %0, %1" : "+v"(d0), "+v"(d2));
    asm("v_permlane32_swap_b32 %0, %1" : "+v"(d1), "+v"(d3));
    asm("v_permlane32_swap_b32 %0, %1" : "+v"(d4), "+v"(d6));
    asm("v_permlane32_swap_b32 %0, %1" : "+v"(d5), "+v"(d7));
    union { unsigned u[4]; bf16x8 v; } pu0, pu1;
    pu0.u[0] = d0; pu0.u[1] = d1; pu0.u[2] = d2; pu0.u[3] = d3;
    pu1.u[0] = d4; pu1.u[1] = d5; pu1.u[2] = d6; pu1.u[3] = d7;

    // ---- bar2: V(kt) landed for ALL waves; K/V(kt+1) (4 loads) still fly ----
    asm volatile("s_waitcnt vmcnt(4)" ::: "memory");
    __builtin_amdgcn_s_barrier();
    __builtin_amdgcn_sched_barrier(0);

    // O += P . V  over this wave's m-half
    __builtin_amdgcn_s_setprio(1);
#pragma unroll
    for (int t = 0; t < 4; ++t) {
      bf16x8 bv0 = *(const bf16x8*)(vB + t * 4096 + vro);
      oacc[t] = __builtin_amdgcn_mfma_f32_32x32x16_bf16(pu0.v, bv0, oacc[t], 0, 0, 0);
      bf16x8 bv1 = *(const bf16x8*)(vB + t * 4096 + (vro ^ 32));
      oacc[t] = __builtin_amdgcn_mfma_f32_32x32x16_bf16(pu1.v, bv1, oacc[t], 0, 0, 0);
    }
    __builtin_amdgcn_s_setprio(0);
    __builtin_amdgcn_sched_barrier(0);
  }
#undef STAGE

  float lsum = (ls[0] + ls[1]) + (ls[2] + ls[3]);
  // merge q2 halves of the row sum: lane (l31,*) -> sum over this wave's 32 m
  lsum += __shfl_xor(lsum, 32, 64);

  // combine the two m-halves through LDS, normalize, coalesced store
  __syncthreads();                          // drains wrap-stage; all tile reads done
  float* cb  = (float*)smem;                // [4][4096] f32 partials = 64KB
  float* cbL = (float*)(smem + 65536);      // [2][128] row sums
  if (w_m == 1) {
    float* my = cb + w_q * 4096;
#pragma unroll
    for (int t = 0; t < 4; ++t)
#pragma unroll
      for (int r = 0; r < 16; ++r)
        my[(t * 16 + r) * 64 + lane] = oacc[t][r];
  }
  cbL[w_m * 128 + w_q * 32 + l31] = lsum;   // both q2 lanes write same value
  __syncthreads();
  if (w_m == 0) {
    const float* pr = cb + w_q * 4096;
    float linv[16];
#pragma unroll
    for (int r = 0; r < 16; ++r) {
      int qr = (r & 3) + ((r >> 2) << 3) + (q2 << 2);
      linv[r] = 1.0f / (cbL[w_q * 32 + qr] + cbL[128 + w_q * 32 + qr]);
    }
    float* ob = out + ((size_t)(b * SEQ) + q0) * DIM;
#pragma unroll
    for (int t = 0; t < 4; ++t)
#pragma unroll
      for (int r = 0; r < 16; ++r) {
        int qr = (r & 3) + ((r >> 2) << 3) + (q2 << 2);
        ob[(size_t)qr * DIM + t * 32 + l31] = (oacc[t][r] + pr[(t * 16 + r) * 64 + lane]) * linv[r];
      }
  }
}

extern "C" void kernel_launch(void* const* d_in, const int* in_sizes, int n_in,
                              void* d_out, int out_size, void* d_ws, size_t ws_size,
                              hipStream_t stream) {
  const float* Q = (const float*)d_in[0];
  const float* K = (const float*)d_in[1];
  const float* V = (const float*)d_in[2];
  float* out = (float*)d_out;

  const size_t elems = (size_t)BATCH * SEQ * DIM;   // 4,194,304
  unsigned short* Kb = (unsigned short*)d_ws;       // 8 MB
  unsigned short* Vt = Kb + elems;                  // 8 MB (ws >= 16 MB)

  const double TEMPERATURE = 11.313708498984761;
  const float scale = (float)(1.4426950408889634 / TEMPERATURE);  // log2(e)/temp on K

  prep_kernel<<<3072, 256, 0, stream>>>(K, V, Kb, Vt, scale);
  attn_kernel<<<dim3(BATCH, SEQ / 128), 512, 0, stream>>>(Q, Kb, Vt, out);
}

// Round 11
// 129.760 us; speedup vs baseline: 1.2660x; 1.0099x over previous
//
#include <hip/hip_runtime.h>

// b=16, n=m=2048, d=dv=128, fp32 in/out, temp=sqrt(128).
// Prep: K -> bf16 scaled by log2e/temp; V -> Vt[b][dv][m] bf16. Q cast in-kernel.
// Attention: swapped S^T = K.Q^T via 32x32x16 bf16 MFMA, P = exp2(S),
// P->A-frag via v_cvt_pk_bf16_f32 + v_permlane32_swap_b32, PV accumulate.
// K/V staged by global_load_lds (linear LDS dest, XOR-swizzled global source).
// Round-11: KVBLK=128 (2 sub-tiles A/B per barrier interval) on R10's 8-wave
// geometry. Per barrier-pair each wave runs 32 MFMAs (QK 2x8-chains + PV 4x4);
// SM_A overlaps QK_B's chain latency (no fences between them); barrier convoys
// per KV element HALVE. V LDS rows widen 128B->256B = 16 XOR slots -> PV reads
// drop from 4-way bank conflict (3 extra cyc/read, confirmed by counter math:
// 2.1M = blocks*tiles*(32K*1 + 32V*3)) to the free 2-way. LDS: K dbuf 2x32KB
// @0/@32768, V dbuf 2x32KB @65536/@98304 = 128KB, 1 block/CU, 8 waves/CU.
// Counted-vmcnt schedule (R4 scheme scaled): STAGE(t+1) [4K then 4V] right
// after bar1; bar1 vmcnt(4) [K(t) landed], bar2 vmcnt(8) [V(t) landed,
// K/V(t+1) flying]. Wrap-staging keeps counts uniform; epilogue __syncthreads
// drains. Overwrite safety: stage targets' last readers were body t-1's
// MFMAs, whose LDS operand reads completed before issue (pre-barrier).
// History: R4 50.6 = R5 = R10 51.6 < R8 52.7 < R9 56.8; externally ~900 TF
// (m214 plain-HIP) proves headroom, so not declaring roofline.
// Block = 8 waves: 4 q-subtiles x 2 m-halves (BQ=128, m-half=64).
// Grid 16x16 = 256 blocks -> 1 block/CU.

#define BATCH 16
#define SEQ   2048
#define DIM   128
#define NT    (SEQ / 128)

typedef short bf16x8 __attribute__((ext_vector_type(8)));
typedef float f32x16 __attribute__((ext_vector_type(16)));

static __device__ __forceinline__ unsigned pk2(float lo, float hi) {
  union { float f; unsigned u; } a, b;
  a.f = lo; b.f = hi;
  return ((b.u + 0x8000u) & 0xffff0000u) | ((a.u + 0x8000u) >> 16);
}
static __device__ __forceinline__ float fast_exp2(float x) {
#if __has_builtin(__builtin_amdgcn_exp2f)
  return __builtin_amdgcn_exp2f(x);
#else
  return exp2f(x);
#endif
}

typedef __attribute__((address_space(1))) const unsigned int g_u32;
typedef __attribute__((address_space(3))) unsigned int l_u32;
static __device__ __forceinline__ void gl2lds16(const unsigned short* g, unsigned short* l) {
  // per-lane global src; wave-uniform LDS base, HW writes base + lane*16
  __builtin_amdgcn_global_load_lds((g_u32*)g, (l_u32*)l, 16, 0, 0);
}

// ---- fused preprocess: blocks [0,2048): K cvt+scale; [2048,3072): V transpose ----
__global__ __launch_bounds__(256)
void prep_kernel(const float* __restrict__ K, const float* __restrict__ V,
                 unsigned short* __restrict__ Kb, unsigned short* __restrict__ Vt,
                 float scale) {
  const int bx = blockIdx.x, tid = threadIdx.x;
  if (bx < 2048) {
    size_t idx = (size_t)bx * 256 + tid;
    const float4* kf = (const float4*)K;
    float4 a = kf[idx * 2], c = kf[idx * 2 + 1];
    uint4 o;
    o.x = pk2(a.x * scale, a.y * scale);
    o.y = pk2(a.z * scale, a.w * scale);
    o.z = pk2(c.x * scale, c.y * scale);
    o.w = pk2(c.z * scale, c.w * scale);
    ((uint4*)Kb)[idx] = o;
  } else {
    __shared__ float tile[128][33];
    const int vb = bx - 2048;                 // 1024 blocks
    const int b = vb >> 6, r = vb & 63;
    const int m0 = (r & 15) * 128, d0 = (r >> 4) * 32;
    const int c = tid & 7, mr = tid >> 3;
    const float* src = V + ((size_t)(b * SEQ) + m0) * DIM + d0;
#pragma unroll
    for (int it = 0; it < 4; ++it) {
      int m = it * 32 + mr;
      float4 x = *(const float4*)(src + (size_t)m * DIM + c * 4);
      tile[m][c * 4 + 0] = x.x; tile[m][c * 4 + 1] = x.y;
      tile[m][c * 4 + 2] = x.z; tile[m][c * 4 + 3] = x.w;
    }
    __syncthreads();
    const int dr = tid >> 3, s = tid & 7;
    unsigned short* dst = Vt + ((size_t)(b * DIM) + d0 + dr) * SEQ + m0;
#pragma unroll
    for (int it = 0; it < 2; ++it) {
      int slot = it * 8 + s;
      uint4 o;
      o.x = pk2(tile[slot * 8 + 0][dr], tile[slot * 8 + 1][dr]);
      o.y = pk2(tile[slot * 8 + 2][dr], tile[slot * 8 + 3][dr]);
      o.z = pk2(tile[slot * 8 + 4][dr], tile[slot * 8 + 5][dr]);
      o.w = pk2(tile[slot * 8 + 6][dr], tile[slot * 8 + 7][dr]);
      *(uint4*)(dst + slot * 8) = o;
    }
  }
}

// ---- main flash attention ----
// LDS (bytes): K bufs @0, @32768 (2x32KB); V bufs @65536, @98304 (2x32KB).
// K buf: 128 rows x 256B linear, [r][x] holds K[m0+r][x ^ ((r&15)<<4)]
// V buf: 128 rows x 256B linear, [dv][x] holds Vt[dv][m0 + (x ^ ((dv&15)<<4))/2]
// Epilogue (after __syncthreads) aliases: cb f32[4][4096] @0 (64KB),
// cbL f32[2][128] @65536. Total 131072 -> 1 block/CU (grid=256), 8 waves/CU.

__global__ __launch_bounds__(512, 2)
void attn_kernel(const float* __restrict__ Qf,
                 const unsigned short* __restrict__ Kb,
                 const unsigned short* __restrict__ Vtb,
                 float* __restrict__ out) {
  __shared__ __align__(1024) unsigned char smem[131072];
  unsigned short* sm16 = (unsigned short*)smem;

  const int tid  = threadIdx.x;
  const int wv   = tid >> 6;                // 0..7
  const int w_q  = wv & 3;                  // q-subtile (32 rows of the 128)
  const int w_m  = wv >> 2;                 // m-half (64 cols of the 128-tile)
  const int lane = tid & 63;
  const int l31  = lane & 31;
  const int q2   = lane >> 5;
  const int b    = blockIdx.x;
  const int q0   = blockIdx.y * 128 + w_q * 32;

  const unsigned short* kb = Kb  + (size_t)b * SEQ * DIM;   // [m][d], pre-scaled
  const unsigned short* vb = Vtb + (size_t)b * SEQ * DIM;   // [dv][m]

  // Q fragments (B-operand of swapped QK^T): lane (l31,q2) holds Q[q0+l31][c*16+q2*8+j]
  bf16x8 aq[8];
  {
    const float* qp = Qf + ((size_t)(b * SEQ) + q0 + l31) * DIM + q2 * 8;
#pragma unroll
    for (int c = 0; c < 8; ++c) {
      float4 x = *(const float4*)(qp + c * 16);
      float4 y = *(const float4*)(qp + c * 16 + 4);
      union { unsigned i[4]; bf16x8 v; } u;
      u.i[0] = pk2(x.x, x.y); u.i[1] = pk2(x.z, x.w);
      u.i[2] = pk2(y.x, y.y); u.i[3] = pk2(y.z, y.w);
      aq[c] = u.v;
    }
  }

  // staging source offsets (ushort units); LDS dest linear, global src
  // pre-swizzled. Both tiles are 32KB = 32 chunks of 1KB; 8 waves x 4 chunks.
  // Chunk ch covers 4 rows (256B each); lane: row ch*4+(lane>>4), slot lane&15.
  unsigned kgo[4], vgo[4];
#pragma unroll
  for (int i = 0; i < 4; ++i) {
    int r = wv * 16 + i * 4 + (lane >> 4);  // 0..127 (K m-row / V dv-row)
    kgo[i] = (unsigned)(r * 128)  + (((lane & 15) ^ (r & 15)) << 3);
    vgo[i] = (unsigned)(r * 2048) + (((lane & 15) ^ (r & 15)) << 3);
  }

  // swizzled read base offsets (bytes, within a buffer)
  const int sw    = (l31 & 15) << 4;
  const int kroA  = ((w_m * 64 + l31) << 8) + ((q2 << 4) ^ sw);  // sub B: +8192
  const int vbase = ((w_m << 7) | (q2 << 4)) ^ sw;  // ^(sub<<6) ^(ks<<5)

  f32x16 oacc[4];
#pragma unroll
  for (int t = 0; t < 4; ++t)
#pragma unroll
    for (int i = 0; i < 16; ++i) oacc[t][i] = 0.0f;
  float ls[4] = {0.0f, 0.0f, 0.0f, 0.0f};

  // K chunks first, then V (vmcnt counting: oldest outstanding = K chunks).
#define STAGE(TK, D) do {                                                    \
    const unsigned short* kt_b = kb + ((size_t)(TK) << 14);                  \
    const unsigned short* vt_b = vb + ((TK) << 7);                           \
    unsigned short* kd = sm16 + (D) * 16384 + wv * 2048;                     \
    unsigned short* vd = sm16 + 32768 + (D) * 16384 + wv * 2048;             \
    _Pragma("unroll")                                                        \
    for (int i = 0; i < 4; ++i) gl2lds16(kt_b + kgo[i], kd + i * 512);       \
    _Pragma("unroll")                                                        \
    for (int i = 0; i < 4; ++i) gl2lds16(vt_b + vgo[i], vd + i * 512);       \
  } while (0)

  // softmax of one 32-m sub-tile: S -> P=exp2 -> packed bf16 A-fragments
#define SM(S, PU0, PU1) do {                                                 \
    float p[16];                                                             \
    _Pragma("unroll")                                                        \
    for (int i = 0; i < 16; ++i) p[i] = fast_exp2(S[i]);                     \
    _Pragma("unroll")                                                        \
    for (int i = 0; i < 4; ++i) {                                            \
      ls[0] += p[4 * i + 0]; ls[1] += p[4 * i + 1];                          \
      ls[2] += p[4 * i + 2]; ls[3] += p[4 * i + 3];                          \
    }                                                                        \
    unsigned d0, d1, d2, d3, d4, d5, d6, d7;                                 \
    asm("v_cvt_pk_bf16_f32 %0, %1, %2" : "=v"(d0) : "v"(p[0]),  "v"(p[1]));  \
    asm("v_cvt_pk_bf16_f32 %0, %1, %2" : "=v"(d1) : "v"(p[2]),  "v"(p[3]));  \
    asm("v_cvt_pk_bf16_f32 %0, %1, %2" : "=v"(d2) : "v"(p[4]),  "v"(p[5]));  \
    asm("v_cvt_pk_bf16_f32 %0, %1, %2" : "=v"(d3) : "v"(p[6]),  "v"(p[7]));  \
    asm("v_cvt_pk_bf16_f32 %0, %1, %2" : "=v"(d4) : "v"(p[8]),  "v"(p[9]));  \
    asm("v_cvt_pk_bf16_f32 %0, %1, %2" : "=v"(d5) : "v"(p[10]), "v"(p[11])); \
    asm("v_cvt_pk_bf16_f32 %0, %1, %2" : "=v"(d6) : "v"(p[12]), "v"(p[13])); \
    asm("v_cvt_pk_bf16_f32 %0, %1, %2" : "=v"(d7) : "v"(p[14]), "v"(p[15])); \
    asm("v_permlane32_swap_b32 %0, %1" : "+v"(d0), "+v"(d2));                \
    asm("v_permlane32_swap_b32 %0, %1" : "+v"(d1), "+v"(d3));                \
    asm("v_permlane32_swap_b32 %0, %1" : "+v"(d4), "+v"(d6));                \
    asm("v_permlane32_swap_b32 %0, %1" : "+v"(d5), "+v"(d7));                \
    PU0.u[0] = d0; PU0.u[1] = d1; PU0.u[2] = d2; PU0.u[3] = d3;              \
    PU1.u[0] = d4; PU1.u[1] = d5; PU1.u[2] = d6; PU1.u[3] = d7;              \
  } while (0)

  STAGE(0, 0);

  for (int kt = 0; kt < NT; ++kt) {
    const int cur = kt & 1;
    // ---- bar1: K(kt) landed for ALL waves; V(kt) (4 loads) still flying ----
    asm volatile("s_waitcnt vmcnt(4)" ::: "memory");
    __builtin_amdgcn_s_barrier();
    __builtin_amdgcn_sched_barrier(0);

    // prefetch next tile (other buffer). Safe: that buffer's last readers were
    // body kt-1's MFMAs (operand ds_reads retired pre-barrier). Stays in
    // flight across bar2 and the next QK. Wrap drained by epilogue.
    STAGE((kt + 1) & (NT - 1), cur ^ 1);
    __builtin_amdgcn_sched_barrier(0);

    const unsigned char* kB = smem + cur * 32768;
    const unsigned char* vB = smem + 65536 + cur * 32768;

    // S^T = K . Q^T for sub-tiles A (m 0..31 of this wave's 64) and B (32..63)
    // lane (l31,q2) holds S[q=l31][m=(r&3)+8*(r>>2)+4*q2] per sub-tile.
    f32x16 sA, sB;
#pragma unroll
    for (int i = 0; i < 16; ++i) { sA[i] = 0.0f; sB[i] = 0.0f; }
    __builtin_amdgcn_s_setprio(1);
#pragma unroll
    for (int c = 0; c < 8; ++c) {
      bf16x8 bk = *(const bf16x8*)(kB + (kroA ^ (c << 5)));
      sA = __builtin_amdgcn_mfma_f32_32x32x16_bf16(bk, aq[c], sA, 0, 0, 0);
    }
    __builtin_amdgcn_s_setprio(0);

    union { unsigned u[4]; bf16x8 v; } puA0, puA1, puB0, puB1;
    SM(sA, puA0, puA1);                     // overlaps QK_B's chain (no fence)

    __builtin_amdgcn_s_setprio(1);
#pragma unroll
    for (int c = 0; c < 8; ++c) {
      bf16x8 bk = *(const bf16x8*)(kB + 8192 + (kroA ^ (c << 5)));
      sB = __builtin_amdgcn_mfma_f32_32x32x16_bf16(bk, aq[c], sB, 0, 0, 0);
    }
    __builtin_amdgcn_s_setprio(0);
    SM(sB, puB0, puB1);

    // ---- bar2: V(kt) landed for ALL waves; K/V(kt+1) (8 loads) still fly ----
    asm volatile("s_waitcnt vmcnt(8)" ::: "memory");
    __builtin_amdgcn_s_barrier();
    __builtin_amdgcn_sched_barrier(0);

    // O += P . V over this wave's m-half: 4 dv-tiles x 4-deep chains
    __builtin_amdgcn_s_setprio(1);
#pragma unroll
    for (int t = 0; t < 4; ++t) {
      const unsigned char* vr = vB + (((t * 32 + l31)) << 8);
      bf16x8 b0 = *(const bf16x8*)(vr + vbase);
      oacc[t] = __builtin_amdgcn_mfma_f32_32x32x16_bf16(puA0.v, b0, oacc[t], 0, 0, 0);
      bf16x8 b1 = *(const bf16x8*)(vr + (vbase ^ 32));
      oacc[t] = __builtin_amdgcn_mfma_f32_32x32x16_bf16(puA1.v, b1, oacc[t], 0, 0, 0);
      bf16x8 b2 = *(const bf16x8*)(vr + (vbase ^ 64));
      oacc[t] = __builtin_amdgcn_mfma_f32_32x32x16_bf16(puB0.v, b2, oacc[t], 0, 0, 0);
      bf16x8 b3 = *(const bf16x8*)(vr + (vbase ^ 96));
      oacc[t] = __builtin_amdgcn_mfma_f32_32x32x16_bf16(puB1.v, b3, oacc[t], 0, 0, 0);
    }
    __builtin_amdgcn_s_setprio(0);
    __builtin_amdgcn_sched_barrier(0);
  }
#undef STAGE
#undef SM

  float lsum = (ls[0] + ls[1]) + (ls[2] + ls[3]);
  // merge q2 halves of the row sum: lane (l31,*) -> sum over this wave's 64 m
  lsum += __shfl_xor(lsum, 32, 64);

  // combine the two m-halves through LDS, normalize, coalesced store
  __syncthreads();                          // drains wrap-stage; all tile reads done
  float* cb  = (float*)smem;                // [4][4096] f32 partials = 64KB
  float* cbL = (float*)(smem + 65536);      // [2][128] row sums
  if (w_m == 1) {
    float* my = cb + w_q * 4096;
#pragma unroll
    for (int t = 0; t < 4; ++t)
#pragma unroll
      for (int r = 0; r < 16; ++r)
        my[(t * 16 + r) * 64 + lane] = oacc[t][r];
  }
  cbL[w_m * 128 + w_q * 32 + l31] = lsum;   // both q2 lanes write same value
  __syncthreads();
  if (w_m == 0) {
    const float* pr = cb + w_q * 4096;
    float linv[16];
#pragma unroll
    for (int r = 0; r < 16; ++r) {
      int qr = (r & 3) + ((r >> 2) << 3) + (q2 << 2);
      linv[r] = 1.0f / (cbL[w_q * 32 + qr] + cbL[128 + w_q * 32 + qr]);
    }
    float* ob = out + ((size_t)(b * SEQ) + q0) * DIM;
#pragma unroll
    for (int t = 0; t < 4; ++t)
#pragma unroll
      for (int r = 0; r < 16; ++r) {
        int qr = (r & 3) + ((r >> 2) << 3) + (q2 << 2);
        ob[(size_t)qr * DIM + t * 32 + l31] = (oacc[t][r] + pr[(t * 16 + r) * 64 + lane]) * linv[r];
      }
  }
}

extern "C" void kernel_launch(void* const* d_in, const int* in_sizes, int n_in,
                              void* d_out, int out_size, void* d_ws, size_t ws_size,
                              hipStream_t stream) {
  const float* Q = (const float*)d_in[0];
  const float* K = (const float*)d_in[1];
  const float* V = (const float*)d_in[2];
  float* out = (float*)d_out;

  const size_t elems = (size_t)BATCH * SEQ * DIM;   // 4,194,304
  unsigned short* Kb = (unsigned short*)d_ws;       // 8 MB
  unsigned short* Vt = Kb + elems;                  // 8 MB (ws >= 16 MB)

  const double TEMPERATURE = 11.313708498984761;
  const float scale = (float)(1.4426950408889634 / TEMPERATURE);  // log2(e)/temp on K

  prep_kernel<<<3072, 256, 0, stream>>>(K, V, Kb, Vt, scale);
  attn_kernel<<<dim3(BATCH, SEQ / 128), 512, 0, stream>>>(Q, Kb, Vt, out);
}